// Round 12
// baseline (328.774 us; speedup 1.0000x reference)
//
#include <hip/hip_runtime.h>

#define D 256
#define NC 64

using u16 = unsigned short;
using u32 = unsigned int;

typedef __attribute__((ext_vector_type(8))) short bfv8;   // 8 bf16 = 16 B
typedef __attribute__((ext_vector_type(4))) float f32x4;
typedef __attribute__((ext_vector_type(2))) int v2i;

__device__ __forceinline__ float bf2f(u32 u) {
  union { u32 i; float f; } v; v.i = u << 16; return v.f;
}
__device__ __forceinline__ u16 f2bf(float f) {
  union { float f; u32 i; } v; v.f = f;
  u32 x = v.i;
  return (u16)((x + 0x7FFFu + ((x >> 16) & 1u)) >> 16);  // RTNE
}
__device__ __forceinline__ u32 pk2(float a, float b) {
  return (u32)f2bf(a) | ((u32)f2bf(b) << 16);
}
__device__ __forceinline__ size_t cmrow(int g) {   // class-major row index
  return (size_t)(((g & 63) << 10) | (g >> 6));
}

__device__ __forceinline__ void gload_lds16(const void* src, void* dst) {
  __builtin_amdgcn_global_load_lds(
      (const __attribute__((address_space(1))) void*)src,
      (__attribute__((address_space(3))) void*)dst, 16, 0, 0);
}

#define K1_LDS 74240     // distp MODE0: 64K + 4K + 512 + nbpart 4K ; gj 71168
#define DISTP_LDS 70144  // MODE1: 64K + 4K + 512

// ---------------------------------------------------------------------------
// Blocked Gauss-Jordan inverse (round-9/10/11 proven body, unchanged).
// ---------------------------------------------------------------------------
__device__ void gj_body(const float* __restrict__ W, float* __restrict__ IW,
                        char* smem) {
  float (*Ml)[20]    = (float(*)[20])smem;                 // 20480 B
  float (*Arow)[256] = (float(*)[256])(smem + 20480);      // 16384 B
  float (*G)[256]    = (float(*)[256])(smem + 36864);      // 16384 B
  u16*  Gfrag        = (u16*)(smem + 53248);               // 16640 B
  float (*Pinv)[20]  = (float(*)[20])(smem + 69888);       // 1280 B
  const int t = threadIdx.x, w = t >> 6, l = t & 63;
  const int lj = l & 15, lh = l >> 4;
  const int r0 = 16 * w;
  const bool lo32 = (l < 32);

  f32x4 x[16];
#pragma unroll
  for (int ct = 0; ct < 16; ++ct)
#pragma unroll
    for (int reg = 0; reg < 4; ++reg)
      x[ct][reg] = W[(size_t)(r0 + 4 * lh + reg) * D + 16 * ct + lj];

  for (int s = 0; s < 16; ++s) {
#pragma unroll
    for (int ct = 0; ct < 16; ++ct)
      if (ct == s)
#pragma unroll
        for (int reg = 0; reg < 4; ++reg)
          Ml[r0 + 4 * lh + reg][lj] = x[ct][reg];
    if (w == s) {
#pragma unroll
      for (int ct = 0; ct < 16; ++ct)
#pragma unroll
        for (int reg = 0; reg < 4; ++reg)
          Arow[4 * lh + reg][16 * ct + lj] = x[ct][reg];
    }
    bfv8 afr;
    {
      const int row = r0 + lj;
      float4 f0 = *(const float4*)&Ml[row][8 * (lh & 1)];
      float4 f1 = *(const float4*)&Ml[row][8 * (lh & 1) + 4];
      const float fv[8] = {f0.x, f0.y, f0.z, f0.w, f1.x, f1.y, f1.z, f1.w};
      union { bfv8 v; u16 e[8]; } A;
      if (lh < 2) {
#pragma unroll
        for (int e = 0; e < 8; ++e) A.e[e] = f2bf(-fv[e]);
      } else {
#pragma unroll
        for (int e = 0; e < 8; ++e) {
          const float hi = bf2f(f2bf(fv[e]));
          A.e[e] = f2bf(-(fv[e] - hi));
        }
      }
      afr = A.v;
    }
    __syncthreads();
    if (t < 16) {
      float p[16];
      {
        float4 rr0 = *(const float4*)&Ml[16 * s + t][0];
        float4 rr1 = *(const float4*)&Ml[16 * s + t][4];
        float4 rr2 = *(const float4*)&Ml[16 * s + t][8];
        float4 rr3 = *(const float4*)&Ml[16 * s + t][12];
        p[0] = rr0.x; p[1] = rr0.y; p[2] = rr0.z; p[3] = rr0.w;
        p[4] = rr1.x; p[5] = rr1.y; p[6] = rr1.z; p[7] = rr1.w;
        p[8] = rr2.x; p[9] = rr2.y; p[10] = rr2.z; p[11] = rr2.w;
        p[12] = rr3.x; p[13] = rr3.y; p[14] = rr3.z; p[15] = rr3.w;
      }
#pragma unroll
      for (int pp = 0; pp < 16; ++pp) {
        float u[16];
#pragma unroll
        for (int j = 0; j < 16; ++j)
          u[j] = __int_as_float(__builtin_amdgcn_readlane(__float_as_int(p[j]), pp));
        const float pv = u[pp];
        const float d = 1.0f / pv;
        if (t == pp) {
#pragma unroll
          for (int j = 0; j < 16; ++j) p[j] = u[j] * d;
          p[pp] = d;
        } else {
          const float md = p[pp] * d;
          u[pp] = pv + 1.0f;
#pragma unroll
          for (int j = 0; j < 16; ++j) p[j] = fmaf(-md, u[j], p[j]);
        }
      }
#pragma unroll
      for (int j = 0; j < 16; ++j) Pinv[t][j] = p[j];
    }
    __syncthreads();
    {
      const bool inC = ((l >> 2) == s);
      const int co = (l & 3) << 2;
      const int gct = l >> 2;
      const int kk = w;
      float4 g = make_float4(0.f, 0.f, 0.f, 0.f);
#pragma unroll
      for (int q = 0; q < 16; ++q) {
        const float pv = Pinv[kk][q];
        const float4 av = *(const float4*)&Arow[q][4 * l];
        g.x = fmaf(pv, av.x, g.x); g.y = fmaf(pv, av.y, g.y);
        g.z = fmaf(pv, av.z, g.z); g.w = fmaf(pv, av.w, g.w);
      }
      if (inC) {
        g.x = Pinv[kk][co + 0] + (kk == co + 0 ? 1.f : 0.f);
        g.y = Pinv[kk][co + 1] + (kk == co + 1 ? 1.f : 0.f);
        g.z = Pinv[kk][co + 2] + (kk == co + 2 ? 1.f : 0.f);
        g.w = Pinv[kk][co + 3] + (kk == co + 3 ? 1.f : 0.f);
      }
      *(float4*)&G[kk][4 * l] = g;
      const int e0 = kk & 7;
      const int lbase = 16 * (kk >> 3);
      const float gv[4] = {g.x, g.y, g.z, g.w};
#pragma unroll
      for (int cc = 0; cc < 4; ++cc) {
        const int cl = 4 * (l & 3) + cc;
        const u16 hi = f2bf(gv[cc]);
        const u16 lo = f2bf(gv[cc] - bf2f(hi));
        Gfrag[gct * 520 + (lbase + cl) * 8 + e0] = hi;
        Gfrag[gct * 520 + (32 + lbase + cl) * 8 + e0] = lo;
      }
    }
    __syncthreads();
    if (w != s) {
#pragma unroll
      for (int ct = 0; ct < 16; ++ct) {
        union { bfv8 v; uint4 u; } B1, B2;
        B1.v = *(const bfv8*)&Gfrag[ct * 520 + l * 8];
#if __has_builtin(__builtin_amdgcn_permlane32_swap)
        {
          v2i r;
          r = __builtin_amdgcn_permlane32_swap((int)B1.u.x, (int)B1.u.x, false, false);
          B2.u.x = lo32 ? (u32)r.y : (u32)r.x;
          r = __builtin_amdgcn_permlane32_swap((int)B1.u.y, (int)B1.u.y, false, false);
          B2.u.y = lo32 ? (u32)r.y : (u32)r.x;
          r = __builtin_amdgcn_permlane32_swap((int)B1.u.z, (int)B1.u.z, false, false);
          B2.u.z = lo32 ? (u32)r.y : (u32)r.x;
          r = __builtin_amdgcn_permlane32_swap((int)B1.u.w, (int)B1.u.w, false, false);
          B2.u.w = lo32 ? (u32)r.y : (u32)r.x;
        }
#else
        B2.v = *(const bfv8*)&Gfrag[ct * 520 + (l ^ 32) * 8];
#endif
        x[ct] = __builtin_amdgcn_mfma_f32_16x16x32_bf16(afr, B1.v, x[ct], 0, 0, 0);
        x[ct] = __builtin_amdgcn_mfma_f32_16x16x32_bf16(afr, B2.v, x[ct], 0, 0, 0);
      }
    } else {
#pragma unroll
      for (int ct = 0; ct < 16; ++ct) {
        if (ct == s) {
#pragma unroll
          for (int reg = 0; reg < 4; ++reg)
            x[ct][reg] = Pinv[4 * lh + reg][lj];
        } else {
#pragma unroll
          for (int reg = 0; reg < 4; ++reg)
            x[ct][reg] = G[4 * lh + reg][16 * ct + lj];
        }
      }
    }
    __syncthreads();
  }
#pragma unroll
  for (int ct = 0; ct < 16; ++ct)
#pragma unroll
    for (int reg = 0; reg < 4; ++reg)
      IW[(size_t)(r0 + 4 * lh + reg) * D + 16 * ct + lj] = x[ct][reg];
}

// ---------------------------------------------------------------------------
// convnorm: f32 row-major -> bf16 class-major + exact f32 row norms.
// ---------------------------------------------------------------------------
__device__ void convnorm_role(const float* __restrict__ P, u16* __restrict__ Pb,
                              float* __restrict__ nrm, int blk) {
  const int tx = threadIdx.x;
  const int r = tx >> 2, q = tx & 3;
  const int g = blk * 256 + r;
  const float* src = P + (size_t)g * D + q * 64;
  u16* dst = Pb + cmrow(g) * D + q * 64;
  float ss = 0.f;
#pragma unroll
  for (int g4 = 0; g4 < 8; ++g4) {
    float4 v0 = *(const float4*)(src + g4 * 8);
    float4 v1 = *(const float4*)(src + g4 * 8 + 4);
    ss = fmaf(v0.x, v0.x, fmaf(v0.y, v0.y, fmaf(v0.z, v0.z, fmaf(v0.w, v0.w, ss))));
    ss = fmaf(v1.x, v1.x, fmaf(v1.y, v1.y, fmaf(v1.z, v1.z, fmaf(v1.w, v1.w, ss))));
    uint4 w4;
    w4.x = pk2(v0.x, v0.y); w4.y = pk2(v0.z, v0.w);
    w4.z = pk2(v1.x, v1.y); w4.w = pk2(v1.z, v1.w);
    *(uint4*)(dst + g4 * 8) = w4;
  }
  ss += __shfl_xor(ss, 1, 64);
  ss += __shfl_xor(ss, 2, 64);
  if (q == 0) nrm[cmrow(g)] = ss;
}

// ---------------------------------------------------------------------------
// distp (r11 proven structure): fused {tile prep + distance + min} per
// (class, j-tile), 1024 thr. A-slices in registers; panel dbuf reuses tile LDS.
// MODE 0 (dir=1, runs under gj): SELF-CONTAINED — B-frags reg-converted from
//   f32 W; panel reg-staged from f32 p2 with inline EXACT norms (nbpart LDS).
// MODE 1 (dir=0): B-frags from bf16 IWb; panel via gload_lds from p1b; norms
//   from global n1 (produced in k1's convnorm role).
// ---------------------------------------------------------------------------
template <int MODE>
__device__ void distp_body(const float* __restrict__ Pj,
                           const float* __restrict__ Wf,
                           const u16* __restrict__ BrowsBF,
                           const float* __restrict__ biasv,
                           const float* __restrict__ PanF,
                           const u16* __restrict__ PanBF,
                           const float* __restrict__ nB,
                           float* __restrict__ pmind, int bid, char* smem) {
  const int lb = (bid & 7) * 64 + (bid >> 3);   // XCD swizzle: class->XCD
  const int c = lb >> 3, jt = lb & 7;
  const int tx = threadIdx.x, ww = tx >> 6, l = tx & 63;
  const int mw = ww >> 3, nw = ww & 7, l4 = l >> 4, lm = l & 15;
  char* Ab = smem;                          // A-stage -> tile -> panel dbuf
  float* nfpart = (float*)(smem + 65536);   // [8][128] (tile-store phase)
  float* minbuf = (float*)(smem + 65536);   // [4][64]  (dist loop)
  float* nAb = (float*)(smem + 69632);      // [128]
  float* nbpart = (float*)(smem + 70144);   // MODE0: [2][8][64]

  auto issue_chunk = [&](int buf, int ch) {  // MODE1 panel stage
#pragma unroll
    for (int u = 0; u < 2; ++u) {
      const int chunk = ww * 2 + u, ks = chunk >> 2, n = chunk & 3;
      const u16* src = PanBF + ((size_t)(c << 10) + ch * 64 + n * 16 + lm) * D
                       + ks * 32 + l4 * 8;
      gload_lds16(src, Ab + buf * 32768 + chunk * 1024);
    }
  };
  auto stage_f32 = [&](int buf, int ch) {    // MODE0 panel stage + norms
#pragma unroll
    for (int u = 0; u < 2; ++u) {
      const int chunk = ww * 2 + u, ks = chunk >> 2, n = chunk & 3;
      const int m = ch * 64 + n * 16 + lm;   // class member index
      const float* src = PanF + ((size_t)m * 64 + c) * D + ks * 32 + l4 * 8;
      float4 v0 = *(const float4*)src;
      float4 v1 = *(const float4*)(src + 4);
      uint4 w4;
      w4.x = pk2(v0.x, v0.y); w4.y = pk2(v0.z, v0.w);
      w4.z = pk2(v1.x, v1.y); w4.w = pk2(v1.z, v1.w);
      *(uint4*)(Ab + buf * 32768 + chunk * 1024 + l * 16) = w4;
      float ss = fmaf(v0.x, v0.x, fmaf(v0.y, v0.y, fmaf(v0.z, v0.z, v0.w * v0.w)));
      ss = fmaf(v1.x, v1.x, fmaf(v1.y, v1.y, fmaf(v1.z, v1.z, fmaf(v1.w, v1.w, ss))));
      ss += __shfl_xor(ss, 16, 64);
      ss += __shfl_xor(ss, 32, 64);
      if (l4 == 0) nbpart[buf * 512 + ks * 64 + n * 16 + lm] = ss;
    }
  };

  // ---- B frags
  bfv8 bfr[2][8];
  if (MODE == 0) {
#pragma unroll
    for (int nf2 = 0; nf2 < 2; ++nf2)
#pragma unroll
      for (int ks = 0; ks < 8; ++ks) {
        const float* wsrc = Wf + (size_t)(nw * 32 + nf2 * 16 + lm) * D + ks * 32 + l4 * 8;
        float4 b0 = *(const float4*)wsrc;
        float4 b1 = *(const float4*)(wsrc + 4);
        union { bfv8 v; uint4 u; } cv;
        cv.u.x = pk2(b0.x, b0.y); cv.u.y = pk2(b0.z, b0.w);
        cv.u.z = pk2(b1.x, b1.y); cv.u.w = pk2(b1.z, b1.w);
        bfr[nf2][ks] = cv.v;
      }
  } else {
#pragma unroll
    for (int nf2 = 0; nf2 < 2; ++nf2)
#pragma unroll
      for (int ks = 0; ks < 8; ++ks)
        bfr[nf2][ks] = *(const bfv8*)(BrowsBF +
            (size_t)(nw * 32 + nf2 * 16 + lm) * D + ks * 32 + l4 * 8);
  }
  // ---- A staging: class-gathered f32 rows -> bf16 frags in LDS
  {
    const int r = tx >> 3, sg = tx & 7;
    const float* arow = Pj + ((size_t)(jt * 128 + r) * NC + c) * D + sg * 32;
#pragma unroll
    for (int g2 = 0; g2 < 4; ++g2) {
      float4 v0 = *(const float4*)(arow + g2 * 8);
      float4 v1 = *(const float4*)(arow + g2 * 8 + 4);
      uint4 w4;
      w4.x = pk2(v0.x, v0.y); w4.y = pk2(v0.z, v0.w);
      w4.z = pk2(v1.x, v1.y); w4.w = pk2(v1.z, v1.w);
      *(uint4*)(Ab + (sg * 8 + (r >> 4)) * 1024 + ((r & 15) + g2 * 16) * 16) = w4;
    }
  }
  __syncthreads();
  const bfv8* A8 = (const bfv8*)Ab;
  f32x4 acc[4][2];
#pragma unroll
  for (int mf = 0; mf < 4; ++mf) {
    acc[mf][0] = f32x4{0.f, 0.f, 0.f, 0.f};
    acc[mf][1] = f32x4{0.f, 0.f, 0.f, 0.f};
  }
#pragma unroll
  for (int ks = 0; ks < 8; ++ks)
#pragma unroll
    for (int mf = 0; mf < 4; ++mf) {
      bfv8 a = A8[(ks * 8 + mw * 4 + mf) * 64 + l];
      acc[mf][0] = __builtin_amdgcn_mfma_f32_16x16x32_bf16(a, bfr[0][ks], acc[mf][0], 0, 0, 0);
      acc[mf][1] = __builtin_amdgcn_mfma_f32_16x16x32_bf16(a, bfr[1][ks], acc[mf][1], 0, 0, 0);
    }
  float bias[2];
  if (MODE == 0) {
#pragma unroll
    for (int nf2 = 0; nf2 < 2; ++nf2)
      bias[nf2] = biasv[nw * 32 + nf2 * 16 + lm];
  } else {
#pragma unroll
    for (int nf2 = 0; nf2 < 2; ++nf2) {
      float pd = 0.f;
#pragma unroll
      for (int ks = 0; ks < 8; ++ks) {
        float4 b0 = *(const float4*)(biasv + ks * 32 + l4 * 8);
        float4 b1 = *(const float4*)(biasv + ks * 32 + l4 * 8 + 4);
        pd = fmaf(b0.x, bf2f((u16)bfr[nf2][ks][0]), pd);
        pd = fmaf(b0.y, bf2f((u16)bfr[nf2][ks][1]), pd);
        pd = fmaf(b0.z, bf2f((u16)bfr[nf2][ks][2]), pd);
        pd = fmaf(b0.w, bf2f((u16)bfr[nf2][ks][3]), pd);
        pd = fmaf(b1.x, bf2f((u16)bfr[nf2][ks][4]), pd);
        pd = fmaf(b1.y, bf2f((u16)bfr[nf2][ks][5]), pd);
        pd = fmaf(b1.z, bf2f((u16)bfr[nf2][ks][6]), pd);
        pd = fmaf(b1.w, bf2f((u16)bfr[nf2][ks][7]), pd);
      }
      pd += __shfl_xor(pd, 16, 64);
      pd += __shfl_xor(pd, 32, 64);
      bias[nf2] = -pd;
    }
  }
  __syncthreads();   // all MFMA reads of Ab done before tile overwrite
  // ---- store computed tile to LDS (A-frag order) + rounded row norms
  u16* tile = (u16*)Ab;
#pragma unroll
  for (int mf = 0; mf < 4; ++mf)
#pragma unroll
    for (int rr = 0; rr < 4; ++rr) {
      const int j = mw * 64 + mf * 16 + l4 * 4 + rr;
      float v2 = 0.f;
#pragma unroll
      for (int nf2 = 0; nf2 < 2; ++nf2) {
        const float v = acc[mf][nf2][rr] + bias[nf2];
        const u16 hv = f2bf(v);
        tile[(((nw * 8 + mw * 4 + mf) << 6) + ((nf2 * 2 + (lm >> 3)) << 4)
              + l4 * 4 + rr) * 8 + (lm & 7)] = hv;
        const float vr = bf2f(hv);
        v2 = fmaf(vr, vr, v2);
      }
      v2 += __shfl_xor(v2, 1, 64);
      v2 += __shfl_xor(v2, 2, 64);
      v2 += __shfl_xor(v2, 4, 64);
      v2 += __shfl_xor(v2, 8, 64);
      if (lm == 0) nfpart[nw * 128 + j] = v2;
    }
  __syncthreads();   // tile visible to all
  // ---- load this wave's A-slice to registers (tile dead after this)
  const int jw = ww >> 2, iw = ww & 3;
  bfv8 afr[2][8];
#pragma unroll
  for (int jj = 0; jj < 2; ++jj)
#pragma unroll
    for (int ks = 0; ks < 8; ++ks)
      afr[jj][ks] = A8[(ks * 8 + jw * 2 + jj) * 64 + l];
  __syncthreads();   // all afr loads done before panel overwrites tile
  if (MODE == 0) stage_f32(0, 0); else issue_chunk(0, 0);
  if (tx < 128) {
    float s = 0.f;
#pragma unroll
    for (int q = 0; q < 8; ++q) s += nfpart[q * 128 + tx];
    nAb[tx] = s;
  }
  __syncthreads();   // chunk-0 staged; nAb ready
  float naj[2][4];
#pragma unroll
  for (int jj = 0; jj < 2; ++jj)
#pragma unroll
    for (int rr = 0; rr < 4; ++rr)
      naj[jj][rr] = nAb[jw * 32 + jj * 16 + l4 * 4 + rr];
  // ---- distance loop over 16 i-chunks of 64
  const float* nBc = (MODE == 1) ? nB + (c << 10) : nullptr;
  const size_t obase = (size_t)(c * 8 + jt) * 1024;
  for (int ch = 0; ch < 16; ++ch) {
    if (ch < 15) {
      if (MODE == 0) stage_f32((ch + 1) & 1, ch + 1);
      else issue_chunk((ch + 1) & 1, ch + 1);
    }
    const bfv8* B8 = (const bfv8*)(Ab + (ch & 1) * 32768);
    f32x4 a2[2];
    a2[0] = f32x4{0.f, 0.f, 0.f, 0.f};
    a2[1] = f32x4{0.f, 0.f, 0.f, 0.f};
#pragma unroll
    for (int ks = 0; ks < 8; ++ks) {
      bfv8 b = B8[(ks * 4 + iw) * 64 + l];
      a2[0] = __builtin_amdgcn_mfma_f32_16x16x32_bf16(afr[0][ks], b, a2[0], 0, 0, 0);
      a2[1] = __builtin_amdgcn_mfma_f32_16x16x32_bf16(afr[1][ks], b, a2[1], 0, 0, 0);
    }
    float nb;
    if (MODE == 0) {
      const float* nbp = nbpart + (ch & 1) * 512;
      nb = nbp[iw * 16 + lm];
#pragma unroll
      for (int ks = 1; ks < 8; ++ks) nb += nbp[ks * 64 + iw * 16 + lm];
    } else {
      nb = nBc[ch * 64 + iw * 16 + lm];
    }
    float mm = 3.0e38f;
#pragma unroll
    for (int jj = 0; jj < 2; ++jj)
#pragma unroll
      for (int rr = 0; rr < 4; ++rr) {
        const float dd = nb + naj[jj][rr] - 2.0f * a2[jj][rr];
        mm = fminf(mm, dd);
      }
    mm = fminf(mm, __shfl_xor(mm, 16, 64));
    mm = fminf(mm, __shfl_xor(mm, 32, 64));
    if (l4 == 0) minbuf[jw * 64 + iw * 16 + lm] = mm;
    __syncthreads();
    if (tx < 64) {
      float m = minbuf[tx];
#pragma unroll
      for (int q = 1; q < 4; ++q) m = fminf(m, minbuf[q * 64 + tx]);
      pmind[obase + ch * 64 + tx] = m;
    }
    __syncthreads();
  }
}

// K1: block 0 = gj; 1..512 = dist dir=1 (fully self-contained); 513..768 =
// convnorm p1 -> p1b, n1 (for K3).
__global__ __launch_bounds__(1024, 1) void k1_kernel(
    const float* __restrict__ p1, const float* __restrict__ p2,
    const float* __restrict__ W, const float* __restrict__ bv,
    float* __restrict__ pmin1, float* __restrict__ IWa,
    u16* __restrict__ p1b, float* __restrict__ n1) {
  extern __shared__ char smem[];
  const int b = blockIdx.x;
  if (b == 0) {
    gj_body(W, IWa, smem);
  } else if (b <= 512) {
    distp_body<0>(p1, W, nullptr, bv, p2, nullptr, nullptr, pmin1, b - 1, smem);
  } else {
    convnorm_role(p1, p1b, n1, b - 513);
  }
}

// Fused Newton-Schulz: Y = X(2I - W X) -> bf16. 32 blocks x 8 columns.
__global__ __launch_bounds__(256) void ns_fused(const float* __restrict__ W,
                                                const float* __restrict__ X,
                                                u16* __restrict__ Yb) {
  __shared__ float Xc[256][8];
  __shared__ float Rc[256][8];
  const int jc = blockIdx.x * 8, t = threadIdx.x;
  {
    float4 xa = *(const float4*)&X[(size_t)t * D + jc];
    float4 xb = *(const float4*)&X[(size_t)t * D + jc + 4];
    Xc[t][0] = xa.x; Xc[t][1] = xa.y; Xc[t][2] = xa.z; Xc[t][3] = xa.w;
    Xc[t][4] = xb.x; Xc[t][5] = xb.y; Xc[t][6] = xb.z; Xc[t][7] = xb.w;
  }
  __syncthreads();
  float r[8] = {0.f, 0.f, 0.f, 0.f, 0.f, 0.f, 0.f, 0.f};
#pragma unroll 4
  for (int k = 0; k < D; ++k) {
    const float wv = W[(size_t)t * D + k];
#pragma unroll
    for (int q = 0; q < 8; ++q) r[q] = fmaf(wv, Xc[k][q], r[q]);
  }
#pragma unroll
  for (int q = 0; q < 8; ++q)
    Rc[t][q] = ((t - jc) == q ? 2.0f : 0.0f) - r[q];
  __syncthreads();
  float y[8] = {0.f, 0.f, 0.f, 0.f, 0.f, 0.f, 0.f, 0.f};
#pragma unroll 4
  for (int k = 0; k < D; ++k) {
    const float xv = X[(size_t)t * D + k];
#pragma unroll
    for (int q = 0; q < 8; ++q) y[q] = fmaf(xv, Rc[k][q], y[q]);
  }
#pragma unroll
  for (int q = 0; q < 8; ++q)
    Yb[(size_t)t * D + jc + q] = f2bf(y[q]);
}

// K3: dist dir=0 (Q in-block from IWb; panel p1b + norms n1)
__global__ __launch_bounds__(1024, 1) void k3_kernel(
    const float* __restrict__ p2, const u16* __restrict__ IWb,
    const float* __restrict__ bv, const u16* __restrict__ p1b,
    const float* __restrict__ n1, float* __restrict__ pmin0) {
  extern __shared__ char smem[];
  distp_body<1>(p2, nullptr, IWb, bv, nullptr, p1b, n1, pmin0, blockIdx.x, smem);
}

// final: out[dir*64+c] = mean_i min_jt pmin[dir][c][jt][i]
__global__ __launch_bounds__(256) void final_kernel(const float* __restrict__ pmin,
                                                    float* __restrict__ out) {
  __shared__ float ws4[4];
  const int dc = blockIdx.x, tx = threadIdx.x;
  const float* base = pmin + (size_t)dc * 8192;
  float s = 0.f;
#pragma unroll
  for (int t = 0; t < 4; ++t) {
    const int i = t * 256 + tx;
    float m = base[i];
#pragma unroll
    for (int j = 1; j < 8; ++j) m = fminf(m, base[j * 1024 + i]);
    s += m;
  }
#pragma unroll
  for (int off = 32; off; off >>= 1) s += __shfl_xor(s, off, 64);
  if ((tx & 63) == 0) ws4[tx >> 6] = s;
  __syncthreads();
  if (tx == 0)
    out[dc] = (ws4[0] + ws4[1] + ws4[2] + ws4[3]) * (1.0f / 1024.0f);
}

extern "C" void kernel_launch(void* const* d_in, const int* in_sizes, int n_in,
                              void* d_out, int out_size, void* d_ws, size_t ws_size,
                              hipStream_t stream) {
  const float* p1 = (const float*)d_in[0];
  const float* p2 = (const float*)d_in[1];
  const float* W  = (const float*)d_in[2];
  const float* bv = (const float*)d_in[3];
  float* out = (float*)d_out;
  char* ws = (char*)d_ws;
  float* n1  = (float*)(ws);                     // 256KB
  float* IWa = (float*)(ws + (256 << 10));       // 256KB
  u16* IWb   = (u16*)(ws + (512 << 10));         // 128KB
  float* pmin = (float*)(ws + (1 << 20));        // 4MB: [dir][c][jt][1024]
  u16* p1b   = (u16*)(ws + (6u << 20));          // 32MB class-major bf16
  float* pmin0 = pmin;                 // dir 0 (source: p1 vs Q)
  float* pmin1 = pmin + 524288;        // dir 1 (target: p2 vs F)

  hipFuncSetAttribute((const void*)k1_kernel,
                      hipFuncAttributeMaxDynamicSharedMemorySize, K1_LDS);
  hipFuncSetAttribute((const void*)k3_kernel,
                      hipFuncAttributeMaxDynamicSharedMemorySize, DISTP_LDS);

  // K1: gj inverse || dist dir=1 (self-contained) || p1 convert + norms
  k1_kernel<<<769, 1024, K1_LDS, stream>>>(p1, p2, W, bv, pmin1, IWa, p1b, n1);
  // fused Newton-Schulz refinement, bf16 output
  ns_fused<<<32, 256, 0, stream>>>(W, IWa, IWb);
  // K3: dist dir=0 (Q from IWb)
  k3_kernel<<<512, 1024, DISTP_LDS, stream>>>(p2, IWb, bv, p1b, n1, pmin0);
  final_kernel<<<128, 256, 0, stream>>>(pmin, out);
}

// Round 13
// 299.481 us; speedup vs baseline: 1.0978x; 1.0978x over previous
//
#include <hip/hip_runtime.h>

#define D 256
#define NC 64

using u16 = unsigned short;
using u32 = unsigned int;

typedef __attribute__((ext_vector_type(8))) short bfv8;   // 8 bf16 = 16 B
typedef __attribute__((ext_vector_type(4))) float f32x4;
typedef __attribute__((ext_vector_type(2))) int v2i;

__device__ __forceinline__ float bf2f(u32 u) {
  union { u32 i; float f; } v; v.i = u << 16; return v.f;
}
__device__ __forceinline__ u16 f2bf(float f) {
  union { float f; u32 i; } v; v.f = f;
  u32 x = v.i;
  return (u16)((x + 0x7FFFu + ((x >> 16) & 1u)) >> 16);  // RTNE
}
__device__ __forceinline__ u32 pk2(float a, float b) {
  return (u32)f2bf(a) | ((u32)f2bf(b) << 16);
}
__device__ __forceinline__ size_t cmrow(int g) {   // class-major row index
  return (size_t)(((g & 63) << 10) | (g >> 6));
}

__device__ __forceinline__ void gload_lds16(const void* src, void* dst) {
  __builtin_amdgcn_global_load_lds(
      (const __attribute__((address_space(1))) void*)src,
      (__attribute__((address_space(3))) void*)dst, 16, 0, 0);
}

#define K1_LDS 71168     // gj 71168 ; distp 70144
#define DISTP_LDS 70144  // tile/panel 64K (shared) + nfpart/minbuf 4K + nA 512

// ---------------------------------------------------------------------------
// Blocked Gauss-Jordan inverse (round-9/10/11 proven body, unchanged).
// ---------------------------------------------------------------------------
__device__ void gj_body(const float* __restrict__ W, float* __restrict__ IW,
                        char* smem) {
  float (*Ml)[20]    = (float(*)[20])smem;                 // 20480 B
  float (*Arow)[256] = (float(*)[256])(smem + 20480);      // 16384 B
  float (*G)[256]    = (float(*)[256])(smem + 36864);      // 16384 B
  u16*  Gfrag        = (u16*)(smem + 53248);               // 16640 B
  float (*Pinv)[20]  = (float(*)[20])(smem + 69888);       // 1280 B
  const int t = threadIdx.x, w = t >> 6, l = t & 63;
  const int lj = l & 15, lh = l >> 4;
  const int r0 = 16 * w;
  const bool lo32 = (l < 32);

  f32x4 x[16];
#pragma unroll
  for (int ct = 0; ct < 16; ++ct)
#pragma unroll
    for (int reg = 0; reg < 4; ++reg)
      x[ct][reg] = W[(size_t)(r0 + 4 * lh + reg) * D + 16 * ct + lj];

  for (int s = 0; s < 16; ++s) {
#pragma unroll
    for (int ct = 0; ct < 16; ++ct)
      if (ct == s)
#pragma unroll
        for (int reg = 0; reg < 4; ++reg)
          Ml[r0 + 4 * lh + reg][lj] = x[ct][reg];
    if (w == s) {
#pragma unroll
      for (int ct = 0; ct < 16; ++ct)
#pragma unroll
        for (int reg = 0; reg < 4; ++reg)
          Arow[4 * lh + reg][16 * ct + lj] = x[ct][reg];
    }
    bfv8 afr;
    {
      const int row = r0 + lj;
      float4 f0 = *(const float4*)&Ml[row][8 * (lh & 1)];
      float4 f1 = *(const float4*)&Ml[row][8 * (lh & 1) + 4];
      const float fv[8] = {f0.x, f0.y, f0.z, f0.w, f1.x, f1.y, f1.z, f1.w};
      union { bfv8 v; u16 e[8]; } A;
      if (lh < 2) {
#pragma unroll
        for (int e = 0; e < 8; ++e) A.e[e] = f2bf(-fv[e]);
      } else {
#pragma unroll
        for (int e = 0; e < 8; ++e) {
          const float hi = bf2f(f2bf(fv[e]));
          A.e[e] = f2bf(-(fv[e] - hi));
        }
      }
      afr = A.v;
    }
    __syncthreads();
    if (t < 16) {
      float p[16];
      {
        float4 rr0 = *(const float4*)&Ml[16 * s + t][0];
        float4 rr1 = *(const float4*)&Ml[16 * s + t][4];
        float4 rr2 = *(const float4*)&Ml[16 * s + t][8];
        float4 rr3 = *(const float4*)&Ml[16 * s + t][12];
        p[0] = rr0.x; p[1] = rr0.y; p[2] = rr0.z; p[3] = rr0.w;
        p[4] = rr1.x; p[5] = rr1.y; p[6] = rr1.z; p[7] = rr1.w;
        p[8] = rr2.x; p[9] = rr2.y; p[10] = rr2.z; p[11] = rr2.w;
        p[12] = rr3.x; p[13] = rr3.y; p[14] = rr3.z; p[15] = rr3.w;
      }
#pragma unroll
      for (int pp = 0; pp < 16; ++pp) {
        float u[16];
#pragma unroll
        for (int j = 0; j < 16; ++j)
          u[j] = __int_as_float(__builtin_amdgcn_readlane(__float_as_int(p[j]), pp));
        const float pv = u[pp];
        const float d = 1.0f / pv;
        if (t == pp) {
#pragma unroll
          for (int j = 0; j < 16; ++j) p[j] = u[j] * d;
          p[pp] = d;
        } else {
          const float md = p[pp] * d;
          u[pp] = pv + 1.0f;
#pragma unroll
          for (int j = 0; j < 16; ++j) p[j] = fmaf(-md, u[j], p[j]);
        }
      }
#pragma unroll
      for (int j = 0; j < 16; ++j) Pinv[t][j] = p[j];
    }
    __syncthreads();
    {
      const bool inC = ((l >> 2) == s);
      const int co = (l & 3) << 2;
      const int gct = l >> 2;
      const int kk = w;
      float4 g = make_float4(0.f, 0.f, 0.f, 0.f);
#pragma unroll
      for (int q = 0; q < 16; ++q) {
        const float pv = Pinv[kk][q];
        const float4 av = *(const float4*)&Arow[q][4 * l];
        g.x = fmaf(pv, av.x, g.x); g.y = fmaf(pv, av.y, g.y);
        g.z = fmaf(pv, av.z, g.z); g.w = fmaf(pv, av.w, g.w);
      }
      if (inC) {
        g.x = Pinv[kk][co + 0] + (kk == co + 0 ? 1.f : 0.f);
        g.y = Pinv[kk][co + 1] + (kk == co + 1 ? 1.f : 0.f);
        g.z = Pinv[kk][co + 2] + (kk == co + 2 ? 1.f : 0.f);
        g.w = Pinv[kk][co + 3] + (kk == co + 3 ? 1.f : 0.f);
      }
      *(float4*)&G[kk][4 * l] = g;
      const int e0 = kk & 7;
      const int lbase = 16 * (kk >> 3);
      const float gv[4] = {g.x, g.y, g.z, g.w};
#pragma unroll
      for (int cc = 0; cc < 4; ++cc) {
        const int cl = 4 * (l & 3) + cc;
        const u16 hi = f2bf(gv[cc]);
        const u16 lo = f2bf(gv[cc] - bf2f(hi));
        Gfrag[gct * 520 + (lbase + cl) * 8 + e0] = hi;
        Gfrag[gct * 520 + (32 + lbase + cl) * 8 + e0] = lo;
      }
    }
    __syncthreads();
    if (w != s) {
#pragma unroll
      for (int ct = 0; ct < 16; ++ct) {
        union { bfv8 v; uint4 u; } B1, B2;
        B1.v = *(const bfv8*)&Gfrag[ct * 520 + l * 8];
#if __has_builtin(__builtin_amdgcn_permlane32_swap)
        {
          v2i r;
          r = __builtin_amdgcn_permlane32_swap((int)B1.u.x, (int)B1.u.x, false, false);
          B2.u.x = lo32 ? (u32)r.y : (u32)r.x;
          r = __builtin_amdgcn_permlane32_swap((int)B1.u.y, (int)B1.u.y, false, false);
          B2.u.y = lo32 ? (u32)r.y : (u32)r.x;
          r = __builtin_amdgcn_permlane32_swap((int)B1.u.z, (int)B1.u.z, false, false);
          B2.u.z = lo32 ? (u32)r.y : (u32)r.x;
          r = __builtin_amdgcn_permlane32_swap((int)B1.u.w, (int)B1.u.w, false, false);
          B2.u.w = lo32 ? (u32)r.y : (u32)r.x;
        }
#else
        B2.v = *(const bfv8*)&Gfrag[ct * 520 + (l ^ 32) * 8];
#endif
        x[ct] = __builtin_amdgcn_mfma_f32_16x16x32_bf16(afr, B1.v, x[ct], 0, 0, 0);
        x[ct] = __builtin_amdgcn_mfma_f32_16x16x32_bf16(afr, B2.v, x[ct], 0, 0, 0);
      }
    } else {
#pragma unroll
      for (int ct = 0; ct < 16; ++ct) {
        if (ct == s) {
#pragma unroll
          for (int reg = 0; reg < 4; ++reg)
            x[ct][reg] = Pinv[4 * lh + reg][lj];
        } else {
#pragma unroll
          for (int reg = 0; reg < 4; ++reg)
            x[ct][reg] = G[4 * lh + reg][16 * ct + lj];
        }
      }
    }
    __syncthreads();
  }
#pragma unroll
  for (int ct = 0; ct < 16; ++ct)
#pragma unroll
    for (int reg = 0; reg < 4; ++reg)
      IW[(size_t)(r0 + 4 * lh + reg) * D + 16 * ct + lj] = x[ct][reg];
}

// ---------------------------------------------------------------------------
// convnorm: f32 row-major -> bf16 class-major + exact f32 row norms.
// ---------------------------------------------------------------------------
__device__ void convnorm_role(const float* __restrict__ P, u16* __restrict__ Pb,
                              float* __restrict__ nrm, int blk) {
  const int tx = threadIdx.x;
  const int r = tx >> 2, q = tx & 3;
  const int g = blk * 256 + r;
  const float* src = P + (size_t)g * D + q * 64;
  u16* dst = Pb + cmrow(g) * D + q * 64;
  float ss = 0.f;
#pragma unroll
  for (int g4 = 0; g4 < 8; ++g4) {
    float4 v0 = *(const float4*)(src + g4 * 8);
    float4 v1 = *(const float4*)(src + g4 * 8 + 4);
    ss = fmaf(v0.x, v0.x, fmaf(v0.y, v0.y, fmaf(v0.z, v0.z, fmaf(v0.w, v0.w, ss))));
    ss = fmaf(v1.x, v1.x, fmaf(v1.y, v1.y, fmaf(v1.z, v1.z, fmaf(v1.w, v1.w, ss))));
    uint4 w4;
    w4.x = pk2(v0.x, v0.y); w4.y = pk2(v0.z, v0.w);
    w4.z = pk2(v1.x, v1.y); w4.w = pk2(v1.z, v1.w);
    *(uint4*)(dst + g4 * 8) = w4;
  }
  ss += __shfl_xor(ss, 1, 64);
  ss += __shfl_xor(ss, 2, 64);
  if (q == 0) nrm[cmrow(g)] = ss;
}

// ---------------------------------------------------------------------------
// distp (round-11 proven structure): fused {tile prep + distance + min} per
// (class, j-tile), 1024 thr. A-slices in registers; panel dbuf reuses tile
// LDS; panel ALWAYS bf16 via gload_lds (r12 lesson: f32 staging too slow).
// MODE 0 (dir=1): B-frags reg-converted from f32 W (r12's one good piece);
//   panel p2b, norms n2. MODE 1 (dir=0): B-frags bf16 IWb; panel p1b, n1.
// ---------------------------------------------------------------------------
template <int MODE>
__device__ void distp_body(const float* __restrict__ Pj,
                           const float* __restrict__ Wf,
                           const u16* __restrict__ BrowsBF,
                           const float* __restrict__ biasv,
                           const u16* __restrict__ PanBF,
                           const float* __restrict__ nB,
                           float* __restrict__ pmind, int bid, char* smem) {
  const int lb = (bid & 7) * 64 + (bid >> 3);   // XCD swizzle: class->XCD
  const int c = lb >> 3, jt = lb & 7;
  const int tx = threadIdx.x, ww = tx >> 6, l = tx & 63;
  const int mw = ww >> 3, nw = ww & 7, l4 = l >> 4, lm = l & 15;
  char* Ab = smem;                          // A-stage -> tile -> panel dbuf
  float* nfpart = (float*)(smem + 65536);   // [8][128] (tile-store phase)
  float* minbuf = (float*)(smem + 65536);   // [4][64]  (dist loop)
  float* nAb = (float*)(smem + 69632);      // [128]

  auto issue_chunk = [&](int buf, int ch) {
#pragma unroll
    for (int u = 0; u < 2; ++u) {
      const int chunk = ww * 2 + u, ks = chunk >> 2, n = chunk & 3;
      const u16* src = PanBF + ((size_t)(c << 10) + ch * 64 + n * 16 + lm) * D
                       + ks * 32 + l4 * 8;
      gload_lds16(src, Ab + buf * 32768 + chunk * 1024);
    }
  };

  // ---- B frags
  bfv8 bfr[2][8];
  if (MODE == 0) {
#pragma unroll
    for (int nf2 = 0; nf2 < 2; ++nf2)
#pragma unroll
      for (int ks = 0; ks < 8; ++ks) {
        const float* wsrc = Wf + (size_t)(nw * 32 + nf2 * 16 + lm) * D + ks * 32 + l4 * 8;
        float4 b0 = *(const float4*)wsrc;
        float4 b1 = *(const float4*)(wsrc + 4);
        union { bfv8 v; uint4 u; } cv;
        cv.u.x = pk2(b0.x, b0.y); cv.u.y = pk2(b0.z, b0.w);
        cv.u.z = pk2(b1.x, b1.y); cv.u.w = pk2(b1.z, b1.w);
        bfr[nf2][ks] = cv.v;
      }
  } else {
#pragma unroll
    for (int nf2 = 0; nf2 < 2; ++nf2)
#pragma unroll
      for (int ks = 0; ks < 8; ++ks)
        bfr[nf2][ks] = *(const bfv8*)(BrowsBF +
            (size_t)(nw * 32 + nf2 * 16 + lm) * D + ks * 32 + l4 * 8);
  }
  // ---- A staging: class-gathered f32 rows -> bf16 frags in LDS
  {
    const int r = tx >> 3, sg = tx & 7;
    const float* arow = Pj + ((size_t)(jt * 128 + r) * NC + c) * D + sg * 32;
#pragma unroll
    for (int g2 = 0; g2 < 4; ++g2) {
      float4 v0 = *(const float4*)(arow + g2 * 8);
      float4 v1 = *(const float4*)(arow + g2 * 8 + 4);
      uint4 w4;
      w4.x = pk2(v0.x, v0.y); w4.y = pk2(v0.z, v0.w);
      w4.z = pk2(v1.x, v1.y); w4.w = pk2(v1.z, v1.w);
      *(uint4*)(Ab + (sg * 8 + (r >> 4)) * 1024 + ((r & 15) + g2 * 16) * 16) = w4;
    }
  }
  __syncthreads();
  const bfv8* A8 = (const bfv8*)Ab;
  f32x4 acc[4][2];
#pragma unroll
  for (int mf = 0; mf < 4; ++mf) {
    acc[mf][0] = f32x4{0.f, 0.f, 0.f, 0.f};
    acc[mf][1] = f32x4{0.f, 0.f, 0.f, 0.f};
  }
#pragma unroll
  for (int ks = 0; ks < 8; ++ks)
#pragma unroll
    for (int mf = 0; mf < 4; ++mf) {
      bfv8 a = A8[(ks * 8 + mw * 4 + mf) * 64 + l];
      acc[mf][0] = __builtin_amdgcn_mfma_f32_16x16x32_bf16(a, bfr[0][ks], acc[mf][0], 0, 0, 0);
      acc[mf][1] = __builtin_amdgcn_mfma_f32_16x16x32_bf16(a, bfr[1][ks], acc[mf][1], 0, 0, 0);
    }
  float bias[2];
  if (MODE == 0) {
#pragma unroll
    for (int nf2 = 0; nf2 < 2; ++nf2)
      bias[nf2] = biasv[nw * 32 + nf2 * 16 + lm];
  } else {
#pragma unroll
    for (int nf2 = 0; nf2 < 2; ++nf2) {
      float pd = 0.f;
#pragma unroll
      for (int ks = 0; ks < 8; ++ks) {
        float4 b0 = *(const float4*)(biasv + ks * 32 + l4 * 8);
        float4 b1 = *(const float4*)(biasv + ks * 32 + l4 * 8 + 4);
        pd = fmaf(b0.x, bf2f((u16)bfr[nf2][ks][0]), pd);
        pd = fmaf(b0.y, bf2f((u16)bfr[nf2][ks][1]), pd);
        pd = fmaf(b0.z, bf2f((u16)bfr[nf2][ks][2]), pd);
        pd = fmaf(b0.w, bf2f((u16)bfr[nf2][ks][3]), pd);
        pd = fmaf(b1.x, bf2f((u16)bfr[nf2][ks][4]), pd);
        pd = fmaf(b1.y, bf2f((u16)bfr[nf2][ks][5]), pd);
        pd = fmaf(b1.z, bf2f((u16)bfr[nf2][ks][6]), pd);
        pd = fmaf(b1.w, bf2f((u16)bfr[nf2][ks][7]), pd);
      }
      pd += __shfl_xor(pd, 16, 64);
      pd += __shfl_xor(pd, 32, 64);
      bias[nf2] = -pd;
    }
  }
  __syncthreads();   // all MFMA reads of Ab done before tile overwrite
  // ---- store computed tile to LDS (A-frag order) + rounded row norms
  u16* tile = (u16*)Ab;
#pragma unroll
  for (int mf = 0; mf < 4; ++mf)
#pragma unroll
    for (int rr = 0; rr < 4; ++rr) {
      const int j = mw * 64 + mf * 16 + l4 * 4 + rr;
      float v2 = 0.f;
#pragma unroll
      for (int nf2 = 0; nf2 < 2; ++nf2) {
        const float v = acc[mf][nf2][rr] + bias[nf2];
        const u16 hv = f2bf(v);
        tile[(((nw * 8 + mw * 4 + mf) << 6) + ((nf2 * 2 + (lm >> 3)) << 4)
              + l4 * 4 + rr) * 8 + (lm & 7)] = hv;
        const float vr = bf2f(hv);
        v2 = fmaf(vr, vr, v2);
      }
      v2 += __shfl_xor(v2, 1, 64);
      v2 += __shfl_xor(v2, 2, 64);
      v2 += __shfl_xor(v2, 4, 64);
      v2 += __shfl_xor(v2, 8, 64);
      if (lm == 0) nfpart[nw * 128 + j] = v2;
    }
  __syncthreads();   // tile visible to all
  // ---- load this wave's A-slice to registers (tile dead after this)
  const int jw = ww >> 2, iw = ww & 3;
  bfv8 afr[2][8];
#pragma unroll
  for (int jj = 0; jj < 2; ++jj)
#pragma unroll
    for (int ks = 0; ks < 8; ++ks)
      afr[jj][ks] = A8[(ks * 8 + jw * 2 + jj) * 64 + l];
  __syncthreads();   // all afr loads done before panel overwrites tile
  issue_chunk(0, 0); // chunk 0 into buf0 (tile region, now dead)
  if (tx < 128) {
    float s = 0.f;
#pragma unroll
    for (int q = 0; q < 8; ++q) s += nfpart[q * 128 + tx];
    nAb[tx] = s;
  }
  __syncthreads();   // chunk-0 loads drained; nAb ready
  float naj[2][4];
#pragma unroll
  for (int jj = 0; jj < 2; ++jj)
#pragma unroll
    for (int rr = 0; rr < 4; ++rr)
      naj[jj][rr] = nAb[jw * 32 + jj * 16 + l4 * 4 + rr];
  // ---- distance loop over 16 i-chunks of 64
  const float* nBc = nB + (c << 10);
  const size_t obase = (size_t)(c * 8 + jt) * 1024;
  for (int ch = 0; ch < 16; ++ch) {
    if (ch < 15) issue_chunk((ch + 1) & 1, ch + 1);
    const bfv8* B8 = (const bfv8*)(Ab + (ch & 1) * 32768);
    f32x4 a2[2];
    a2[0] = f32x4{0.f, 0.f, 0.f, 0.f};
    a2[1] = f32x4{0.f, 0.f, 0.f, 0.f};
#pragma unroll
    for (int ks = 0; ks < 8; ++ks) {
      bfv8 b = B8[(ks * 4 + iw) * 64 + l];
      a2[0] = __builtin_amdgcn_mfma_f32_16x16x32_bf16(afr[0][ks], b, a2[0], 0, 0, 0);
      a2[1] = __builtin_amdgcn_mfma_f32_16x16x32_bf16(afr[1][ks], b, a2[1], 0, 0, 0);
    }
    const float nb = nBc[ch * 64 + iw * 16 + lm];
    float mm = 3.0e38f;
#pragma unroll
    for (int jj = 0; jj < 2; ++jj)
#pragma unroll
      for (int rr = 0; rr < 4; ++rr) {
        const float dd = nb + naj[jj][rr] - 2.0f * a2[jj][rr];
        mm = fminf(mm, dd);
      }
    mm = fminf(mm, __shfl_xor(mm, 16, 64));
    mm = fminf(mm, __shfl_xor(mm, 32, 64));
    if (l4 == 0) minbuf[jw * 64 + iw * 16 + lm] = mm;
    __syncthreads();
    if (tx < 64) {
      float m = minbuf[tx];
#pragma unroll
      for (int q = 1; q < 4; ++q) m = fminf(m, minbuf[q * 64 + tx]);
      pmind[obase + ch * 64 + tx] = m;
    }
    __syncthreads();
  }
}

// K0: 256 blocks = convnorm(p2 -> p2b, n2)
__global__ __launch_bounds__(1024, 1) void k0_kernel(
    const float* __restrict__ p2, u16* __restrict__ p2b,
    float* __restrict__ n2) {
  convnorm_role(p2, p2b, n2, blockIdx.x);
}

// K1: block 0 = gj; 1..512 = dist dir=1 (W in-reg, panel p2b); 513..768 =
// convnorm p1 -> p1b, n1 (for K3).
__global__ __launch_bounds__(1024, 1) void k1_kernel(
    const float* __restrict__ p1, const float* __restrict__ W,
    const float* __restrict__ bv, const u16* __restrict__ p2b,
    const float* __restrict__ n2, float* __restrict__ pmin1,
    float* __restrict__ IWa, u16* __restrict__ p1b, float* __restrict__ n1) {
  extern __shared__ char smem[];
  const int b = blockIdx.x;
  if (b == 0) {
    gj_body(W, IWa, smem);
  } else if (b <= 512) {
    distp_body<0>(p1, W, nullptr, bv, p2b, n2, pmin1, b - 1, smem);
  } else {
    convnorm_role(p1, p1b, n1, b - 513);
  }
}

// Fused Newton-Schulz: Y = X(2I - W X) -> bf16. 32 blocks x 8 columns.
__global__ __launch_bounds__(256) void ns_fused(const float* __restrict__ W,
                                                const float* __restrict__ X,
                                                u16* __restrict__ Yb) {
  __shared__ float Xc[256][8];
  __shared__ float Rc[256][8];
  const int jc = blockIdx.x * 8, t = threadIdx.x;
  {
    float4 xa = *(const float4*)&X[(size_t)t * D + jc];
    float4 xb = *(const float4*)&X[(size_t)t * D + jc + 4];
    Xc[t][0] = xa.x; Xc[t][1] = xa.y; Xc[t][2] = xa.z; Xc[t][3] = xa.w;
    Xc[t][4] = xb.x; Xc[t][5] = xb.y; Xc[t][6] = xb.z; Xc[t][7] = xb.w;
  }
  __syncthreads();
  float r[8] = {0.f, 0.f, 0.f, 0.f, 0.f, 0.f, 0.f, 0.f};
#pragma unroll 4
  for (int k = 0; k < D; ++k) {
    const float wv = W[(size_t)t * D + k];
#pragma unroll
    for (int q = 0; q < 8; ++q) r[q] = fmaf(wv, Xc[k][q], r[q]);
  }
#pragma unroll
  for (int q = 0; q < 8; ++q)
    Rc[t][q] = ((t - jc) == q ? 2.0f : 0.0f) - r[q];
  __syncthreads();
  float y[8] = {0.f, 0.f, 0.f, 0.f, 0.f, 0.f, 0.f, 0.f};
#pragma unroll 4
  for (int k = 0; k < D; ++k) {
    const float xv = X[(size_t)t * D + k];
#pragma unroll
    for (int q = 0; q < 8; ++q) y[q] = fmaf(xv, Rc[k][q], y[q]);
  }
#pragma unroll
  for (int q = 0; q < 8; ++q)
    Yb[(size_t)t * D + jc + q] = f2bf(y[q]);
}

// K3: dist dir=0 (Q in-block from IWb; panel p1b + norms n1)
__global__ __launch_bounds__(1024, 1) void k3_kernel(
    const float* __restrict__ p2, const u16* __restrict__ IWb,
    const float* __restrict__ bv, const u16* __restrict__ p1b,
    const float* __restrict__ n1, float* __restrict__ pmin0) {
  extern __shared__ char smem[];
  distp_body<1>(p2, nullptr, IWb, bv, p1b, n1, pmin0, blockIdx.x, smem);
}

// final: out[dir*64+c] = mean_i min_jt pmin[dir][c][jt][i]
__global__ __launch_bounds__(256) void final_kernel(const float* __restrict__ pmin,
                                                    float* __restrict__ out) {
  __shared__ float ws4[4];
  const int dc = blockIdx.x, tx = threadIdx.x;
  const float* base = pmin + (size_t)dc * 8192;
  float s = 0.f;
#pragma unroll
  for (int t = 0; t < 4; ++t) {
    const int i = t * 256 + tx;
    float m = base[i];
#pragma unroll
    for (int j = 1; j < 8; ++j) m = fminf(m, base[j * 1024 + i]);
    s += m;
  }
#pragma unroll
  for (int off = 32; off; off >>= 1) s += __shfl_xor(s, off, 64);
  if ((tx & 63) == 0) ws4[tx >> 6] = s;
  __syncthreads();
  if (tx == 0)
    out[dc] = (ws4[0] + ws4[1] + ws4[2] + ws4[3]) * (1.0f / 1024.0f);
}

extern "C" void kernel_launch(void* const* d_in, const int* in_sizes, int n_in,
                              void* d_out, int out_size, void* d_ws, size_t ws_size,
                              hipStream_t stream) {
  const float* p1 = (const float*)d_in[0];
  const float* p2 = (const float*)d_in[1];
  const float* W  = (const float*)d_in[2];
  const float* bv = (const float*)d_in[3];
  float* out = (float*)d_out;
  char* ws = (char*)d_ws;
  float* n1  = (float*)(ws);                     // 256KB
  float* n2  = (float*)(ws + (256 << 10));       // 256KB
  float* IWa = (float*)(ws + (512 << 10));       // 256KB
  u16* IWb   = (u16*)(ws + (768 << 10));         // 128KB
  float* pmin = (float*)(ws + (1 << 20));        // 4MB: [dir][c][jt][1024]
  u16* p1b   = (u16*)(ws + (6u << 20));          // 32MB class-major bf16
  u16* p2b   = (u16*)(ws + (38u << 20));         // 32MB
  float* pmin0 = pmin;                 // dir 0 (source: p1 vs Q)
  float* pmin1 = pmin + 524288;        // dir 1 (target: p2 vs F)

  hipFuncSetAttribute((const void*)k1_kernel,
                      hipFuncAttributeMaxDynamicSharedMemorySize, K1_LDS);
  hipFuncSetAttribute((const void*)k3_kernel,
                      hipFuncAttributeMaxDynamicSharedMemorySize, DISTP_LDS);

  // K0: p2 convert + norms
  k0_kernel<<<256, 1024, 0, stream>>>(p2, p2b, n2);
  // K1: gj inverse || dist dir=1 || p1 convert + norms
  k1_kernel<<<769, 1024, K1_LDS, stream>>>(p1, W, bv, p2b, n2,
                                           pmin1, IWa, p1b, n1);
  // fused Newton-Schulz refinement, bf16 output
  ns_fused<<<32, 256, 0, stream>>>(W, IWa, IWb);
  // K3: dist dir=0 (Q from IWb)
  k3_kernel<<<512, 1024, DISTP_LDS, stream>>>(p2, IWb, bv, p1b, n1, pmin0);
  final_kernel<<<128, 256, 0, stream>>>(pmin, out);
}

// Round 14
// 280.491 us; speedup vs baseline: 1.1721x; 1.0677x over previous
//
#include <hip/hip_runtime.h>

#define D 256
#define NC 64

using u16 = unsigned short;
using u32 = unsigned int;

typedef __attribute__((ext_vector_type(8))) short bfv8;   // 8 bf16 = 16 B
typedef __attribute__((ext_vector_type(4))) float f32x4;
typedef __attribute__((ext_vector_type(2))) int v2i;

__device__ __forceinline__ float bf2f(u32 u) {
  union { u32 i; float f; } v; v.i = u << 16; return v.f;
}
__device__ __forceinline__ u16 f2bf(float f) {
  union { float f; u32 i; } v; v.f = f;
  u32 x = v.i;
  return (u16)((x + 0x7FFFu + ((x >> 16) & 1u)) >> 16);  // RTNE
}
__device__ __forceinline__ u32 pk2(float a, float b) {
  return (u32)f2bf(a) | ((u32)f2bf(b) << 16);
}
__device__ __forceinline__ size_t cmrow(int g) {   // class-major row index
  return (size_t)(((g & 63) << 10) | (g >> 6));
}

__device__ __forceinline__ void gload_lds16(const void* src, void* dst) {
  __builtin_amdgcn_global_load_lds(
      (const __attribute__((address_space(1))) void*)src,
      (__attribute__((address_space(3))) void*)dst, 16, 0, 0);
}

#define K1_LDS 71168     // gj 71168 ; distp 70144
#define DISTP_LDS 70144  // tile/panel 64K (shared) + nfpart/minbuf 4K + nA 512

// ---------------------------------------------------------------------------
// Blocked Gauss-Jordan inverse (round-9/10/11 proven body, unchanged).
// ---------------------------------------------------------------------------
__device__ void gj_body(const float* __restrict__ W, float* __restrict__ IW,
                        char* smem) {
  float (*Ml)[20]    = (float(*)[20])smem;                 // 20480 B
  float (*Arow)[256] = (float(*)[256])(smem + 20480);      // 16384 B
  float (*G)[256]    = (float(*)[256])(smem + 36864);      // 16384 B
  u16*  Gfrag        = (u16*)(smem + 53248);               // 16640 B
  float (*Pinv)[20]  = (float(*)[20])(smem + 69888);       // 1280 B
  const int t = threadIdx.x, w = t >> 6, l = t & 63;
  const int lj = l & 15, lh = l >> 4;
  const int r0 = 16 * w;
  const bool lo32 = (l < 32);

  f32x4 x[16];
#pragma unroll
  for (int ct = 0; ct < 16; ++ct)
#pragma unroll
    for (int reg = 0; reg < 4; ++reg)
      x[ct][reg] = W[(size_t)(r0 + 4 * lh + reg) * D + 16 * ct + lj];

  for (int s = 0; s < 16; ++s) {
#pragma unroll
    for (int ct = 0; ct < 16; ++ct)
      if (ct == s)
#pragma unroll
        for (int reg = 0; reg < 4; ++reg)
          Ml[r0 + 4 * lh + reg][lj] = x[ct][reg];
    if (w == s) {
#pragma unroll
      for (int ct = 0; ct < 16; ++ct)
#pragma unroll
        for (int reg = 0; reg < 4; ++reg)
          Arow[4 * lh + reg][16 * ct + lj] = x[ct][reg];
    }
    bfv8 afr;
    {
      const int row = r0 + lj;
      float4 f0 = *(const float4*)&Ml[row][8 * (lh & 1)];
      float4 f1 = *(const float4*)&Ml[row][8 * (lh & 1) + 4];
      const float fv[8] = {f0.x, f0.y, f0.z, f0.w, f1.x, f1.y, f1.z, f1.w};
      union { bfv8 v; u16 e[8]; } A;
      if (lh < 2) {
#pragma unroll
        for (int e = 0; e < 8; ++e) A.e[e] = f2bf(-fv[e]);
      } else {
#pragma unroll
        for (int e = 0; e < 8; ++e) {
          const float hi = bf2f(f2bf(fv[e]));
          A.e[e] = f2bf(-(fv[e] - hi));
        }
      }
      afr = A.v;
    }
    __syncthreads();
    if (t < 16) {
      float p[16];
      {
        float4 rr0 = *(const float4*)&Ml[16 * s + t][0];
        float4 rr1 = *(const float4*)&Ml[16 * s + t][4];
        float4 rr2 = *(const float4*)&Ml[16 * s + t][8];
        float4 rr3 = *(const float4*)&Ml[16 * s + t][12];
        p[0] = rr0.x; p[1] = rr0.y; p[2] = rr0.z; p[3] = rr0.w;
        p[4] = rr1.x; p[5] = rr1.y; p[6] = rr1.z; p[7] = rr1.w;
        p[8] = rr2.x; p[9] = rr2.y; p[10] = rr2.z; p[11] = rr2.w;
        p[12] = rr3.x; p[13] = rr3.y; p[14] = rr3.z; p[15] = rr3.w;
      }
#pragma unroll
      for (int pp = 0; pp < 16; ++pp) {
        float u[16];
#pragma unroll
        for (int j = 0; j < 16; ++j)
          u[j] = __int_as_float(__builtin_amdgcn_readlane(__float_as_int(p[j]), pp));
        const float pv = u[pp];
        const float d = 1.0f / pv;
        if (t == pp) {
#pragma unroll
          for (int j = 0; j < 16; ++j) p[j] = u[j] * d;
          p[pp] = d;
        } else {
          const float md = p[pp] * d;
          u[pp] = pv + 1.0f;
#pragma unroll
          for (int j = 0; j < 16; ++j) p[j] = fmaf(-md, u[j], p[j]);
        }
      }
#pragma unroll
      for (int j = 0; j < 16; ++j) Pinv[t][j] = p[j];
    }
    __syncthreads();
    {
      const bool inC = ((l >> 2) == s);
      const int co = (l & 3) << 2;
      const int gct = l >> 2;
      const int kk = w;
      float4 g = make_float4(0.f, 0.f, 0.f, 0.f);
#pragma unroll
      for (int q = 0; q < 16; ++q) {
        const float pv = Pinv[kk][q];
        const float4 av = *(const float4*)&Arow[q][4 * l];
        g.x = fmaf(pv, av.x, g.x); g.y = fmaf(pv, av.y, g.y);
        g.z = fmaf(pv, av.z, g.z); g.w = fmaf(pv, av.w, g.w);
      }
      if (inC) {
        g.x = Pinv[kk][co + 0] + (kk == co + 0 ? 1.f : 0.f);
        g.y = Pinv[kk][co + 1] + (kk == co + 1 ? 1.f : 0.f);
        g.z = Pinv[kk][co + 2] + (kk == co + 2 ? 1.f : 0.f);
        g.w = Pinv[kk][co + 3] + (kk == co + 3 ? 1.f : 0.f);
      }
      *(float4*)&G[kk][4 * l] = g;
      const int e0 = kk & 7;
      const int lbase = 16 * (kk >> 3);
      const float gv[4] = {g.x, g.y, g.z, g.w};
#pragma unroll
      for (int cc = 0; cc < 4; ++cc) {
        const int cl = 4 * (l & 3) + cc;
        const u16 hi = f2bf(gv[cc]);
        const u16 lo = f2bf(gv[cc] - bf2f(hi));
        Gfrag[gct * 520 + (lbase + cl) * 8 + e0] = hi;
        Gfrag[gct * 520 + (32 + lbase + cl) * 8 + e0] = lo;
      }
    }
    __syncthreads();
    if (w != s) {
#pragma unroll
      for (int ct = 0; ct < 16; ++ct) {
        union { bfv8 v; uint4 u; } B1, B2;
        B1.v = *(const bfv8*)&Gfrag[ct * 520 + l * 8];
#if __has_builtin(__builtin_amdgcn_permlane32_swap)
        {
          v2i r;
          r = __builtin_amdgcn_permlane32_swap((int)B1.u.x, (int)B1.u.x, false, false);
          B2.u.x = lo32 ? (u32)r.y : (u32)r.x;
          r = __builtin_amdgcn_permlane32_swap((int)B1.u.y, (int)B1.u.y, false, false);
          B2.u.y = lo32 ? (u32)r.y : (u32)r.x;
          r = __builtin_amdgcn_permlane32_swap((int)B1.u.z, (int)B1.u.z, false, false);
          B2.u.z = lo32 ? (u32)r.y : (u32)r.x;
          r = __builtin_amdgcn_permlane32_swap((int)B1.u.w, (int)B1.u.w, false, false);
          B2.u.w = lo32 ? (u32)r.y : (u32)r.x;
        }
#else
        B2.v = *(const bfv8*)&Gfrag[ct * 520 + (l ^ 32) * 8];
#endif
        x[ct] = __builtin_amdgcn_mfma_f32_16x16x32_bf16(afr, B1.v, x[ct], 0, 0, 0);
        x[ct] = __builtin_amdgcn_mfma_f32_16x16x32_bf16(afr, B2.v, x[ct], 0, 0, 0);
      }
    } else {
#pragma unroll
      for (int ct = 0; ct < 16; ++ct) {
        if (ct == s) {
#pragma unroll
          for (int reg = 0; reg < 4; ++reg)
            x[ct][reg] = Pinv[4 * lh + reg][lj];
        } else {
#pragma unroll
          for (int reg = 0; reg < 4; ++reg)
            x[ct][reg] = G[4 * lh + reg][16 * ct + lj];
        }
      }
    }
    __syncthreads();
  }
#pragma unroll
  for (int ct = 0; ct < 16; ++ct)
#pragma unroll
    for (int reg = 0; reg < 4; ++reg)
      IW[(size_t)(r0 + 4 * lh + reg) * D + 16 * ct + lj] = x[ct][reg];
}

// ---------------------------------------------------------------------------
// convnorm: f32 row-major -> bf16 class-major + exact f32 row norms.
// ---------------------------------------------------------------------------
__device__ void convnorm_role(const float* __restrict__ P, u16* __restrict__ Pb,
                              float* __restrict__ nrm, int blk) {
  const int tx = threadIdx.x;
  const int r = tx >> 2, q = tx & 3;
  const int g = blk * 256 + r;
  const float* src = P + (size_t)g * D + q * 64;
  u16* dst = Pb + cmrow(g) * D + q * 64;
  float ss = 0.f;
#pragma unroll
  for (int g4 = 0; g4 < 8; ++g4) {
    float4 v0 = *(const float4*)(src + g4 * 8);
    float4 v1 = *(const float4*)(src + g4 * 8 + 4);
    ss = fmaf(v0.x, v0.x, fmaf(v0.y, v0.y, fmaf(v0.z, v0.z, fmaf(v0.w, v0.w, ss))));
    ss = fmaf(v1.x, v1.x, fmaf(v1.y, v1.y, fmaf(v1.z, v1.z, fmaf(v1.w, v1.w, ss))));
    uint4 w4;
    w4.x = pk2(v0.x, v0.y); w4.y = pk2(v0.z, v0.w);
    w4.z = pk2(v1.x, v1.y); w4.w = pk2(v1.z, v1.w);
    *(uint4*)(dst + g4 * 8) = w4;
  }
  ss += __shfl_xor(ss, 1, 64);
  ss += __shfl_xor(ss, 2, 64);
  if (q == 0) nrm[cmrow(g)] = ss;
}

// ---------------------------------------------------------------------------
// distp (round-11 measured-optimal): fused {tile prep + distance + min} per
// (class, j-tile), 1024 thr. B-frags from bf16 Brows global (Wb or IWb);
// A-slices in registers; panel bf16 via gload_lds; dbuf reuses tile LDS.
// ---------------------------------------------------------------------------
template <int MODE>
__device__ void distp_body(const float* __restrict__ Pj,
                           const u16* __restrict__ Brows,
                           const float* __restrict__ biasv,
                           const u16* __restrict__ PanBF,
                           const float* __restrict__ nB,
                           float* __restrict__ pmind, int bid, char* smem) {
  const int lb = (bid & 7) * 64 + (bid >> 3);   // XCD swizzle: class->XCD
  const int c = lb >> 3, jt = lb & 7;
  const int tx = threadIdx.x, ww = tx >> 6, l = tx & 63;
  const int mw = ww >> 3, nw = ww & 7, l4 = l >> 4, lm = l & 15;
  char* Ab = smem;                          // A-stage -> tile -> panel dbuf
  float* nfpart = (float*)(smem + 65536);   // [8][128] (tile-store phase)
  float* minbuf = (float*)(smem + 65536);   // [4][64]  (dist loop)
  float* nAb = (float*)(smem + 69632);      // [128]

  auto issue_chunk = [&](int buf, int ch) {
#pragma unroll
    for (int u = 0; u < 2; ++u) {
      const int chunk = ww * 2 + u, ks = chunk >> 2, n = chunk & 3;
      const u16* src = PanBF + ((size_t)(c << 10) + ch * 64 + n * 16 + lm) * D
                       + ks * 32 + l4 * 8;
      gload_lds16(src, Ab + buf * 32768 + chunk * 1024);
    }
  };

  // ---- B frags from bf16 Brows (global, L2-hot)
  bfv8 bfr[2][8];
#pragma unroll
  for (int nf2 = 0; nf2 < 2; ++nf2)
#pragma unroll
    for (int ks = 0; ks < 8; ++ks)
      bfr[nf2][ks] = *(const bfv8*)(Brows +
          (size_t)(nw * 32 + nf2 * 16 + lm) * D + ks * 32 + l4 * 8);
  // ---- A staging: class-gathered f32 rows -> bf16 frags in LDS
  {
    const int r = tx >> 3, sg = tx & 7;
    const float* arow = Pj + ((size_t)(jt * 128 + r) * NC + c) * D + sg * 32;
#pragma unroll
    for (int g2 = 0; g2 < 4; ++g2) {
      float4 v0 = *(const float4*)(arow + g2 * 8);
      float4 v1 = *(const float4*)(arow + g2 * 8 + 4);
      uint4 w4;
      w4.x = pk2(v0.x, v0.y); w4.y = pk2(v0.z, v0.w);
      w4.z = pk2(v1.x, v1.y); w4.w = pk2(v1.z, v1.w);
      *(uint4*)(Ab + (sg * 8 + (r >> 4)) * 1024 + ((r & 15) + g2 * 16) * 16) = w4;
    }
  }
  __syncthreads();
  const bfv8* A8 = (const bfv8*)Ab;
  f32x4 acc[4][2];
#pragma unroll
  for (int mf = 0; mf < 4; ++mf) {
    acc[mf][0] = f32x4{0.f, 0.f, 0.f, 0.f};
    acc[mf][1] = f32x4{0.f, 0.f, 0.f, 0.f};
  }
#pragma unroll
  for (int ks = 0; ks < 8; ++ks)
#pragma unroll
    for (int mf = 0; mf < 4; ++mf) {
      bfv8 a = A8[(ks * 8 + mw * 4 + mf) * 64 + l];
      acc[mf][0] = __builtin_amdgcn_mfma_f32_16x16x32_bf16(a, bfr[0][ks], acc[mf][0], 0, 0, 0);
      acc[mf][1] = __builtin_amdgcn_mfma_f32_16x16x32_bf16(a, bfr[1][ks], acc[mf][1], 0, 0, 0);
    }
  float bias[2];
  if (MODE == 0) {
#pragma unroll
    for (int nf2 = 0; nf2 < 2; ++nf2)
      bias[nf2] = biasv[nw * 32 + nf2 * 16 + lm];
  } else {
#pragma unroll
    for (int nf2 = 0; nf2 < 2; ++nf2) {
      float pd = 0.f;
#pragma unroll
      for (int ks = 0; ks < 8; ++ks) {
        float4 b0 = *(const float4*)(biasv + ks * 32 + l4 * 8);
        float4 b1 = *(const float4*)(biasv + ks * 32 + l4 * 8 + 4);
        pd = fmaf(b0.x, bf2f((u16)bfr[nf2][ks][0]), pd);
        pd = fmaf(b0.y, bf2f((u16)bfr[nf2][ks][1]), pd);
        pd = fmaf(b0.z, bf2f((u16)bfr[nf2][ks][2]), pd);
        pd = fmaf(b0.w, bf2f((u16)bfr[nf2][ks][3]), pd);
        pd = fmaf(b1.x, bf2f((u16)bfr[nf2][ks][4]), pd);
        pd = fmaf(b1.y, bf2f((u16)bfr[nf2][ks][5]), pd);
        pd = fmaf(b1.z, bf2f((u16)bfr[nf2][ks][6]), pd);
        pd = fmaf(b1.w, bf2f((u16)bfr[nf2][ks][7]), pd);
      }
      pd += __shfl_xor(pd, 16, 64);
      pd += __shfl_xor(pd, 32, 64);
      bias[nf2] = -pd;
    }
  }
  __syncthreads();   // all MFMA reads of Ab done before tile overwrite
  // ---- store computed tile to LDS (A-frag order) + rounded row norms
  u16* tile = (u16*)Ab;
#pragma unroll
  for (int mf = 0; mf < 4; ++mf)
#pragma unroll
    for (int rr = 0; rr < 4; ++rr) {
      const int j = mw * 64 + mf * 16 + l4 * 4 + rr;
      float v2 = 0.f;
#pragma unroll
      for (int nf2 = 0; nf2 < 2; ++nf2) {
        const float v = acc[mf][nf2][rr] + bias[nf2];
        const u16 hv = f2bf(v);
        tile[(((nw * 8 + mw * 4 + mf) << 6) + ((nf2 * 2 + (lm >> 3)) << 4)
              + l4 * 4 + rr) * 8 + (lm & 7)] = hv;
        const float vr = bf2f(hv);
        v2 = fmaf(vr, vr, v2);
      }
      v2 += __shfl_xor(v2, 1, 64);
      v2 += __shfl_xor(v2, 2, 64);
      v2 += __shfl_xor(v2, 4, 64);
      v2 += __shfl_xor(v2, 8, 64);
      if (lm == 0) nfpart[nw * 128 + j] = v2;
    }
  __syncthreads();   // tile visible to all
  // ---- load this wave's A-slice to registers (tile dead after this)
  const int jw = ww >> 2, iw = ww & 3;
  bfv8 afr[2][8];
#pragma unroll
  for (int jj = 0; jj < 2; ++jj)
#pragma unroll
    for (int ks = 0; ks < 8; ++ks)
      afr[jj][ks] = A8[(ks * 8 + jw * 2 + jj) * 64 + l];
  __syncthreads();   // all afr loads done before panel overwrites tile
  issue_chunk(0, 0); // chunk 0 into buf0 (tile region, now dead)
  if (tx < 128) {
    float s = 0.f;
#pragma unroll
    for (int q = 0; q < 8; ++q) s += nfpart[q * 128 + tx];
    nAb[tx] = s;
  }
  __syncthreads();   // chunk-0 loads drained; nAb ready
  float naj[2][4];
#pragma unroll
  for (int jj = 0; jj < 2; ++jj)
#pragma unroll
    for (int rr = 0; rr < 4; ++rr)
      naj[jj][rr] = nAb[jw * 32 + jj * 16 + l4 * 4 + rr];
  // ---- distance loop over 16 i-chunks of 64
  const float* nBc = nB + (c << 10);
  const size_t obase = (size_t)(c * 8 + jt) * 1024;
  for (int ch = 0; ch < 16; ++ch) {
    if (ch < 15) issue_chunk((ch + 1) & 1, ch + 1);
    const bfv8* B8 = (const bfv8*)(Ab + (ch & 1) * 32768);
    f32x4 a2[2];
    a2[0] = f32x4{0.f, 0.f, 0.f, 0.f};
    a2[1] = f32x4{0.f, 0.f, 0.f, 0.f};
#pragma unroll
    for (int ks = 0; ks < 8; ++ks) {
      bfv8 b = B8[(ks * 4 + iw) * 64 + l];
      a2[0] = __builtin_amdgcn_mfma_f32_16x16x32_bf16(afr[0][ks], b, a2[0], 0, 0, 0);
      a2[1] = __builtin_amdgcn_mfma_f32_16x16x32_bf16(afr[1][ks], b, a2[1], 0, 0, 0);
    }
    const float nb = nBc[ch * 64 + iw * 16 + lm];
    float mm = 3.0e38f;
#pragma unroll
    for (int jj = 0; jj < 2; ++jj)
#pragma unroll
      for (int rr = 0; rr < 4; ++rr) {
        const float dd = nb + naj[jj][rr] - 2.0f * a2[jj][rr];
        mm = fminf(mm, dd);
      }
    mm = fminf(mm, __shfl_xor(mm, 16, 64));
    mm = fminf(mm, __shfl_xor(mm, 32, 64));
    if (l4 == 0) minbuf[jw * 64 + iw * 16 + lm] = mm;
    __syncthreads();
    if (tx < 64) {
      float m = minbuf[tx];
#pragma unroll
      for (int q = 1; q < 4; ++q) m = fminf(m, minbuf[q * 64 + tx]);
      pmind[obase + ch * 64 + tx] = m;
    }
    __syncthreads();
  }
}

// K0: blocks 0..255 = convnorm(p2 -> p2b, n2); block 256 = W -> bf16 Wb
__global__ __launch_bounds__(1024, 1) void k0_kernel(
    const float* __restrict__ p2, u16* __restrict__ p2b,
    float* __restrict__ n2, const float* __restrict__ W,
    u16* __restrict__ Wb) {
  if (blockIdx.x < 256) {
    convnorm_role(p2, p2b, n2, blockIdx.x);
  } else {
    const int t = threadIdx.x;
#pragma unroll
    for (int k = 0; k < 64; ++k) Wb[k * 1024 + t] = f2bf(W[k * 1024 + t]);
  }
}

// K1: block 0 = gj; 1..512 = dist dir=1 (F in-block from Wb, panel p2b);
// 513..768 = convnorm p1 -> p1b, n1 (for K3).
__global__ __launch_bounds__(1024, 1) void k1_kernel(
    const float* __restrict__ p1, const float* __restrict__ W,
    const u16* __restrict__ Wb, const float* __restrict__ bv,
    const u16* __restrict__ p2b, const float* __restrict__ n2,
    float* __restrict__ pmin1, float* __restrict__ IWa,
    u16* __restrict__ p1b, float* __restrict__ n1) {
  extern __shared__ char smem[];
  const int b = blockIdx.x;
  if (b == 0) {
    gj_body(W, IWa, smem);
  } else if (b <= 512) {
    distp_body<0>(p1, Wb, bv, p2b, n2, pmin1, b - 1, smem);
  } else {
    convnorm_role(p1, p1b, n1, b - 513);
  }
}

// Fused Newton-Schulz: Y = X(2I - W X) -> bf16. 32 blocks x 8 columns.
__global__ __launch_bounds__(256) void ns_fused(const float* __restrict__ W,
                                                const float* __restrict__ X,
                                                u16* __restrict__ Yb) {
  __shared__ float Xc[256][8];
  __shared__ float Rc[256][8];
  const int jc = blockIdx.x * 8, t = threadIdx.x;
  {
    float4 xa = *(const float4*)&X[(size_t)t * D + jc];
    float4 xb = *(const float4*)&X[(size_t)t * D + jc + 4];
    Xc[t][0] = xa.x; Xc[t][1] = xa.y; Xc[t][2] = xa.z; Xc[t][3] = xa.w;
    Xc[t][4] = xb.x; Xc[t][5] = xb.y; Xc[t][6] = xb.z; Xc[t][7] = xb.w;
  }
  __syncthreads();
  float r[8] = {0.f, 0.f, 0.f, 0.f, 0.f, 0.f, 0.f, 0.f};
#pragma unroll 4
  for (int k = 0; k < D; ++k) {
    const float wv = W[(size_t)t * D + k];
#pragma unroll
    for (int q = 0; q < 8; ++q) r[q] = fmaf(wv, Xc[k][q], r[q]);
  }
#pragma unroll
  for (int q = 0; q < 8; ++q)
    Rc[t][q] = ((t - jc) == q ? 2.0f : 0.0f) - r[q];
  __syncthreads();
  float y[8] = {0.f, 0.f, 0.f, 0.f, 0.f, 0.f, 0.f, 0.f};
#pragma unroll 4
  for (int k = 0; k < D; ++k) {
    const float xv = X[(size_t)t * D + k];
#pragma unroll
    for (int q = 0; q < 8; ++q) y[q] = fmaf(xv, Rc[k][q], y[q]);
  }
#pragma unroll
  for (int q = 0; q < 8; ++q)
    Yb[(size_t)t * D + jc + q] = f2bf(y[q]);
}

// K3: dist dir=0 (Q in-block from IWb; panel p1b + norms n1)
__global__ __launch_bounds__(1024, 1) void k3_kernel(
    const float* __restrict__ p2, const u16* __restrict__ IWb,
    const float* __restrict__ bv, const u16* __restrict__ p1b,
    const float* __restrict__ n1, float* __restrict__ pmin0) {
  extern __shared__ char smem[];
  distp_body<1>(p2, IWb, bv, p1b, n1, pmin0, blockIdx.x, smem);
}

// final: out[dir*64+c] = mean_i min_jt pmin[dir][c][jt][i]
__global__ __launch_bounds__(256) void final_kernel(const float* __restrict__ pmin,
                                                    float* __restrict__ out) {
  __shared__ float ws4[4];
  const int dc = blockIdx.x, tx = threadIdx.x;
  const float* base = pmin + (size_t)dc * 8192;
  float s = 0.f;
#pragma unroll
  for (int t = 0; t < 4; ++t) {
    const int i = t * 256 + tx;
    float m = base[i];
#pragma unroll
    for (int j = 1; j < 8; ++j) m = fminf(m, base[j * 1024 + i]);
    s += m;
  }
#pragma unroll
  for (int off = 32; off; off >>= 1) s += __shfl_xor(s, off, 64);
  if ((tx & 63) == 0) ws4[tx >> 6] = s;
  __syncthreads();
  if (tx == 0)
    out[dc] = (ws4[0] + ws4[1] + ws4[2] + ws4[3]) * (1.0f / 1024.0f);
}

extern "C" void kernel_launch(void* const* d_in, const int* in_sizes, int n_in,
                              void* d_out, int out_size, void* d_ws, size_t ws_size,
                              hipStream_t stream) {
  const float* p1 = (const float*)d_in[0];
  const float* p2 = (const float*)d_in[1];
  const float* W  = (const float*)d_in[2];
  const float* bv = (const float*)d_in[3];
  float* out = (float*)d_out;
  char* ws = (char*)d_ws;
  float* n1  = (float*)(ws);                     // 256KB
  float* n2  = (float*)(ws + (256 << 10));       // 256KB
  u16* Wb    = (u16*)(ws + (512 << 10));         // 128KB
  u16* IWb   = (u16*)(ws + (640 << 10));         // 128KB
  float* IWa = (float*)(ws + (768 << 10));       // 256KB
  float* pmin = (float*)(ws + (1 << 20));        // 4MB: [dir][c][jt][1024]
  u16* p1b   = (u16*)(ws + (6u << 20));          // 32MB class-major bf16
  u16* p2b   = (u16*)(ws + (38u << 20));         // 32MB
  float* pmin0 = pmin;                 // dir 0 (source: p1 vs Q)
  float* pmin1 = pmin + 524288;        // dir 1 (target: p2 vs F)

  hipFuncSetAttribute((const void*)k1_kernel,
                      hipFuncAttributeMaxDynamicSharedMemorySize, K1_LDS);
  hipFuncSetAttribute((const void*)k3_kernel,
                      hipFuncAttributeMaxDynamicSharedMemorySize, DISTP_LDS);

  // K0: p2 convert + norms, W -> bf16
  k0_kernel<<<257, 1024, 0, stream>>>(p2, p2b, n2, W, Wb);
  // K1: gj inverse || dist dir=1 || p1 convert + norms
  k1_kernel<<<769, 1024, K1_LDS, stream>>>(p1, W, Wb, bv, p2b, n2,
                                           pmin1, IWa, p1b, n1);
  // fused Newton-Schulz refinement, bf16 output
  ns_fused<<<32, 256, 0, stream>>>(W, IWa, IWb);
  // K3: dist dir=0 (Q from IWb)
  k3_kernel<<<512, 1024, DISTP_LDS, stream>>>(p2, IWb, bv, p1b, n1, pmin0);
  final_kernel<<<128, 256, 0, stream>>>(pmin, out);
}

// Round 15
// 279.640 us; speedup vs baseline: 1.1757x; 1.0030x over previous
//
#include <hip/hip_runtime.h>

#define D 256
#define NC 64

using u16 = unsigned short;
using u32 = unsigned int;

typedef __attribute__((ext_vector_type(8))) short bfv8;   // 8 bf16 = 16 B
typedef __attribute__((ext_vector_type(4))) float f32x4;
typedef __attribute__((ext_vector_type(2))) int v2i;

__device__ __forceinline__ float bf2f(u32 u) {
  union { u32 i; float f; } v; v.i = u << 16; return v.f;
}
__device__ __forceinline__ u16 f2bf(float f) {
  union { float f; u32 i; } v; v.f = f;
  u32 x = v.i;
  return (u16)((x + 0x7FFFu + ((x >> 16) & 1u)) >> 16);  // RTNE
}
__device__ __forceinline__ u32 pk2(float a, float b) {
  return (u32)f2bf(a) | ((u32)f2bf(b) << 16);
}
__device__ __forceinline__ size_t cmrow(int g) {   // class-major row index
  return (size_t)(((g & 63) << 10) | (g >> 6));
}

__device__ __forceinline__ void gload_lds16(const void* src, void* dst) {
  __builtin_amdgcn_global_load_lds(
      (const __attribute__((address_space(1))) void*)src,
      (__attribute__((address_space(3))) void*)dst, 16, 0, 0);
}

#define K1_LDS 72192     // gj 71168 ; distp 71680
#define DISTP_LDS 71680  // tile/panel 64K + nfpart 4K (minbuf 2K aliased) + nA 512 + pad

// ---------------------------------------------------------------------------
// Blocked Gauss-Jordan inverse (round-9..14 proven body, unchanged).
// ---------------------------------------------------------------------------
__device__ void gj_body(const float* __restrict__ W, float* __restrict__ IW,
                        char* smem) {
  float (*Ml)[20]    = (float(*)[20])smem;                 // 20480 B
  float (*Arow)[256] = (float(*)[256])(smem + 20480);      // 16384 B
  float (*G)[256]    = (float(*)[256])(smem + 36864);      // 16384 B
  u16*  Gfrag        = (u16*)(smem + 53248);               // 16640 B
  float (*Pinv)[20]  = (float(*)[20])(smem + 69888);       // 1280 B
  const int t = threadIdx.x, w = t >> 6, l = t & 63;
  const int lj = l & 15, lh = l >> 4;
  const int r0 = 16 * w;
  const bool lo32 = (l < 32);

  f32x4 x[16];
#pragma unroll
  for (int ct = 0; ct < 16; ++ct)
#pragma unroll
    for (int reg = 0; reg < 4; ++reg)
      x[ct][reg] = W[(size_t)(r0 + 4 * lh + reg) * D + 16 * ct + lj];

  for (int s = 0; s < 16; ++s) {
#pragma unroll
    for (int ct = 0; ct < 16; ++ct)
      if (ct == s)
#pragma unroll
        for (int reg = 0; reg < 4; ++reg)
          Ml[r0 + 4 * lh + reg][lj] = x[ct][reg];
    if (w == s) {
#pragma unroll
      for (int ct = 0; ct < 16; ++ct)
#pragma unroll
        for (int reg = 0; reg < 4; ++reg)
          Arow[4 * lh + reg][16 * ct + lj] = x[ct][reg];
    }
    bfv8 afr;
    {
      const int row = r0 + lj;
      float4 f0 = *(const float4*)&Ml[row][8 * (lh & 1)];
      float4 f1 = *(const float4*)&Ml[row][8 * (lh & 1) + 4];
      const float fv[8] = {f0.x, f0.y, f0.z, f0.w, f1.x, f1.y, f1.z, f1.w};
      union { bfv8 v; u16 e[8]; } A;
      if (lh < 2) {
#pragma unroll
        for (int e = 0; e < 8; ++e) A.e[e] = f2bf(-fv[e]);
      } else {
#pragma unroll
        for (int e = 0; e < 8; ++e) {
          const float hi = bf2f(f2bf(fv[e]));
          A.e[e] = f2bf(-(fv[e] - hi));
        }
      }
      afr = A.v;
    }
    __syncthreads();
    if (t < 16) {
      float p[16];
      {
        float4 rr0 = *(const float4*)&Ml[16 * s + t][0];
        float4 rr1 = *(const float4*)&Ml[16 * s + t][4];
        float4 rr2 = *(const float4*)&Ml[16 * s + t][8];
        float4 rr3 = *(const float4*)&Ml[16 * s + t][12];
        p[0] = rr0.x; p[1] = rr0.y; p[2] = rr0.z; p[3] = rr0.w;
        p[4] = rr1.x; p[5] = rr1.y; p[6] = rr1.z; p[7] = rr1.w;
        p[8] = rr2.x; p[9] = rr2.y; p[10] = rr2.z; p[11] = rr2.w;
        p[12] = rr3.x; p[13] = rr3.y; p[14] = rr3.z; p[15] = rr3.w;
      }
#pragma unroll
      for (int pp = 0; pp < 16; ++pp) {
        float u[16];
#pragma unroll
        for (int j = 0; j < 16; ++j)
          u[j] = __int_as_float(__builtin_amdgcn_readlane(__float_as_int(p[j]), pp));
        const float pv = u[pp];
        const float d = 1.0f / pv;
        if (t == pp) {
#pragma unroll
          for (int j = 0; j < 16; ++j) p[j] = u[j] * d;
          p[pp] = d;
        } else {
          const float md = p[pp] * d;
          u[pp] = pv + 1.0f;
#pragma unroll
          for (int j = 0; j < 16; ++j) p[j] = fmaf(-md, u[j], p[j]);
        }
      }
#pragma unroll
      for (int j = 0; j < 16; ++j) Pinv[t][j] = p[j];
    }
    __syncthreads();
    {
      const bool inC = ((l >> 2) == s);
      const int co = (l & 3) << 2;
      const int gct = l >> 2;
      const int kk = w;
      float4 g = make_float4(0.f, 0.f, 0.f, 0.f);
#pragma unroll
      for (int q = 0; q < 16; ++q) {
        const float pv = Pinv[kk][q];
        const float4 av = *(const float4*)&Arow[q][4 * l];
        g.x = fmaf(pv, av.x, g.x); g.y = fmaf(pv, av.y, g.y);
        g.z = fmaf(pv, av.z, g.z); g.w = fmaf(pv, av.w, g.w);
      }
      if (inC) {
        g.x = Pinv[kk][co + 0] + (kk == co + 0 ? 1.f : 0.f);
        g.y = Pinv[kk][co + 1] + (kk == co + 1 ? 1.f : 0.f);
        g.z = Pinv[kk][co + 2] + (kk == co + 2 ? 1.f : 0.f);
        g.w = Pinv[kk][co + 3] + (kk == co + 3 ? 1.f : 0.f);
      }
      *(float4*)&G[kk][4 * l] = g;
      const int e0 = kk & 7;
      const int lbase = 16 * (kk >> 3);
      const float gv[4] = {g.x, g.y, g.z, g.w};
#pragma unroll
      for (int cc = 0; cc < 4; ++cc) {
        const int cl = 4 * (l & 3) + cc;
        const u16 hi = f2bf(gv[cc]);
        const u16 lo = f2bf(gv[cc] - bf2f(hi));
        Gfrag[gct * 520 + (lbase + cl) * 8 + e0] = hi;
        Gfrag[gct * 520 + (32 + lbase + cl) * 8 + e0] = lo;
      }
    }
    __syncthreads();
    if (w != s) {
#pragma unroll
      for (int ct = 0; ct < 16; ++ct) {
        union { bfv8 v; uint4 u; } B1, B2;
        B1.v = *(const bfv8*)&Gfrag[ct * 520 + l * 8];
#if __has_builtin(__builtin_amdgcn_permlane32_swap)
        {
          v2i r;
          r = __builtin_amdgcn_permlane32_swap((int)B1.u.x, (int)B1.u.x, false, false);
          B2.u.x = lo32 ? (u32)r.y : (u32)r.x;
          r = __builtin_amdgcn_permlane32_swap((int)B1.u.y, (int)B1.u.y, false, false);
          B2.u.y = lo32 ? (u32)r.y : (u32)r.x;
          r = __builtin_amdgcn_permlane32_swap((int)B1.u.z, (int)B1.u.z, false, false);
          B2.u.z = lo32 ? (u32)r.y : (u32)r.x;
          r = __builtin_amdgcn_permlane32_swap((int)B1.u.w, (int)B1.u.w, false, false);
          B2.u.w = lo32 ? (u32)r.y : (u32)r.x;
        }
#else
        B2.v = *(const bfv8*)&Gfrag[ct * 520 + (l ^ 32) * 8];
#endif
        x[ct] = __builtin_amdgcn_mfma_f32_16x16x32_bf16(afr, B1.v, x[ct], 0, 0, 0);
        x[ct] = __builtin_amdgcn_mfma_f32_16x16x32_bf16(afr, B2.v, x[ct], 0, 0, 0);
      }
    } else {
#pragma unroll
      for (int ct = 0; ct < 16; ++ct) {
        if (ct == s) {
#pragma unroll
          for (int reg = 0; reg < 4; ++reg)
            x[ct][reg] = Pinv[4 * lh + reg][lj];
        } else {
#pragma unroll
          for (int reg = 0; reg < 4; ++reg)
            x[ct][reg] = G[4 * lh + reg][16 * ct + lj];
        }
      }
    }
    __syncthreads();
  }
#pragma unroll
  for (int ct = 0; ct < 16; ++ct)
#pragma unroll
    for (int reg = 0; reg < 4; ++reg)
      IW[(size_t)(r0 + 4 * lh + reg) * D + 16 * ct + lj] = x[ct][reg];
}

// ---------------------------------------------------------------------------
// convnorm: f32 row-major -> bf16 class-major + exact f32 row norms.
// ---------------------------------------------------------------------------
__device__ void convnorm_role(const float* __restrict__ P, u16* __restrict__ Pb,
                              float* __restrict__ nrm, int blk) {
  const int tx = threadIdx.x;
  const int r = tx >> 2, q = tx & 3;
  const int g = blk * 256 + r;
  const float* src = P + (size_t)g * D + q * 64;
  u16* dst = Pb + cmrow(g) * D + q * 64;
  float ss = 0.f;
#pragma unroll
  for (int g4 = 0; g4 < 8; ++g4) {
    float4 v0 = *(const float4*)(src + g4 * 8);
    float4 v1 = *(const float4*)(src + g4 * 8 + 4);
    ss = fmaf(v0.x, v0.x, fmaf(v0.y, v0.y, fmaf(v0.z, v0.z, fmaf(v0.w, v0.w, ss))));
    ss = fmaf(v1.x, v1.x, fmaf(v1.y, v1.y, fmaf(v1.z, v1.z, fmaf(v1.w, v1.w, ss))));
    uint4 w4;
    w4.x = pk2(v0.x, v0.y); w4.y = pk2(v0.z, v0.w);
    w4.z = pk2(v1.x, v1.y); w4.w = pk2(v1.z, v1.w);
    *(uint4*)(dst + g4 * 8) = w4;
  }
  ss += __shfl_xor(ss, 1, 64);
  ss += __shfl_xor(ss, 2, 64);
  if (q == 0) nrm[cmrow(g)] = ss;
}

// ---------------------------------------------------------------------------
// distp (r11/r14 structure + ping-pong minbuf: ONE barrier per dist chunk).
// ---------------------------------------------------------------------------
template <int MODE>
__device__ void distp_body(const float* __restrict__ Pj,
                           const u16* __restrict__ Brows,
                           const float* __restrict__ biasv,
                           const u16* __restrict__ PanBF,
                           const float* __restrict__ nB,
                           float* __restrict__ pmind, int bid, char* smem) {
  const int lb = (bid & 7) * 64 + (bid >> 3);   // XCD swizzle: class->XCD
  const int c = lb >> 3, jt = lb & 7;
  const int tx = threadIdx.x, ww = tx >> 6, l = tx & 63;
  const int mw = ww >> 3, nw = ww & 7, l4 = l >> 4, lm = l & 15;
  char* Ab = smem;                          // A-stage -> tile -> panel dbuf
  float* nfpart = (float*)(smem + 65536);   // [8][128] (tile-store phase)
  float* minbuf = (float*)(smem + 65536);   // [2][4][64] ping-pong (aliased)
  float* nAb = (float*)(smem + 70144);      // [128]

  auto issue_chunk = [&](int buf, int ch) {
#pragma unroll
    for (int u = 0; u < 2; ++u) {
      const int chunk = ww * 2 + u, ks = chunk >> 2, n = chunk & 3;
      const u16* src = PanBF + ((size_t)(c << 10) + ch * 64 + n * 16 + lm) * D
                       + ks * 32 + l4 * 8;
      gload_lds16(src, Ab + buf * 32768 + chunk * 1024);
    }
  };

  // ---- B frags from bf16 Brows (global, L2-hot)
  bfv8 bfr[2][8];
#pragma unroll
  for (int nf2 = 0; nf2 < 2; ++nf2)
#pragma unroll
    for (int ks = 0; ks < 8; ++ks)
      bfr[nf2][ks] = *(const bfv8*)(Brows +
          (size_t)(nw * 32 + nf2 * 16 + lm) * D + ks * 32 + l4 * 8);
  // ---- A staging: class-gathered f32 rows -> bf16 frags in LDS
  {
    const int r = tx >> 3, sg = tx & 7;
    const float* arow = Pj + ((size_t)(jt * 128 + r) * NC + c) * D + sg * 32;
#pragma unroll
    for (int g2 = 0; g2 < 4; ++g2) {
      float4 v0 = *(const float4*)(arow + g2 * 8);
      float4 v1 = *(const float4*)(arow + g2 * 8 + 4);
      uint4 w4;
      w4.x = pk2(v0.x, v0.y); w4.y = pk2(v0.z, v0.w);
      w4.z = pk2(v1.x, v1.y); w4.w = pk2(v1.z, v1.w);
      *(uint4*)(Ab + (sg * 8 + (r >> 4)) * 1024 + ((r & 15) + g2 * 16) * 16) = w4;
    }
  }
  __syncthreads();
  const bfv8* A8 = (const bfv8*)Ab;
  f32x4 acc[4][2];
#pragma unroll
  for (int mf = 0; mf < 4; ++mf) {
    acc[mf][0] = f32x4{0.f, 0.f, 0.f, 0.f};
    acc[mf][1] = f32x4{0.f, 0.f, 0.f, 0.f};
  }
#pragma unroll
  for (int ks = 0; ks < 8; ++ks)
#pragma unroll
    for (int mf = 0; mf < 4; ++mf) {
      bfv8 a = A8[(ks * 8 + mw * 4 + mf) * 64 + l];
      acc[mf][0] = __builtin_amdgcn_mfma_f32_16x16x32_bf16(a, bfr[0][ks], acc[mf][0], 0, 0, 0);
      acc[mf][1] = __builtin_amdgcn_mfma_f32_16x16x32_bf16(a, bfr[1][ks], acc[mf][1], 0, 0, 0);
    }
  float bias[2];
  if (MODE == 0) {
#pragma unroll
    for (int nf2 = 0; nf2 < 2; ++nf2)
      bias[nf2] = biasv[nw * 32 + nf2 * 16 + lm];
  } else {
#pragma unroll
    for (int nf2 = 0; nf2 < 2; ++nf2) {
      float pd = 0.f;
#pragma unroll
      for (int ks = 0; ks < 8; ++ks) {
        float4 b0 = *(const float4*)(biasv + ks * 32 + l4 * 8);
        float4 b1 = *(const float4*)(biasv + ks * 32 + l4 * 8 + 4);
        pd = fmaf(b0.x, bf2f((u16)bfr[nf2][ks][0]), pd);
        pd = fmaf(b0.y, bf2f((u16)bfr[nf2][ks][1]), pd);
        pd = fmaf(b0.z, bf2f((u16)bfr[nf2][ks][2]), pd);
        pd = fmaf(b0.w, bf2f((u16)bfr[nf2][ks][3]), pd);
        pd = fmaf(b1.x, bf2f((u16)bfr[nf2][ks][4]), pd);
        pd = fmaf(b1.y, bf2f((u16)bfr[nf2][ks][5]), pd);
        pd = fmaf(b1.z, bf2f((u16)bfr[nf2][ks][6]), pd);
        pd = fmaf(b1.w, bf2f((u16)bfr[nf2][ks][7]), pd);
      }
      pd += __shfl_xor(pd, 16, 64);
      pd += __shfl_xor(pd, 32, 64);
      bias[nf2] = -pd;
    }
  }
  __syncthreads();   // all MFMA reads of Ab done before tile overwrite
  // ---- store computed tile to LDS (A-frag order) + rounded row norms
  u16* tile = (u16*)Ab;
#pragma unroll
  for (int mf = 0; mf < 4; ++mf)
#pragma unroll
    for (int rr = 0; rr < 4; ++rr) {
      const int j = mw * 64 + mf * 16 + l4 * 4 + rr;
      float v2 = 0.f;
#pragma unroll
      for (int nf2 = 0; nf2 < 2; ++nf2) {
        const float v = acc[mf][nf2][rr] + bias[nf2];
        const u16 hv = f2bf(v);
        tile[(((nw * 8 + mw * 4 + mf) << 6) + ((nf2 * 2 + (lm >> 3)) << 4)
              + l4 * 4 + rr) * 8 + (lm & 7)] = hv;
        const float vr = bf2f(hv);
        v2 = fmaf(vr, vr, v2);
      }
      v2 += __shfl_xor(v2, 1, 64);
      v2 += __shfl_xor(v2, 2, 64);
      v2 += __shfl_xor(v2, 4, 64);
      v2 += __shfl_xor(v2, 8, 64);
      if (lm == 0) nfpart[nw * 128 + j] = v2;
    }
  __syncthreads();   // tile visible to all
  // ---- load this wave's A-slice to registers (tile dead after this)
  const int jw = ww >> 2, iw = ww & 3;
  bfv8 afr[2][8];
#pragma unroll
  for (int jj = 0; jj < 2; ++jj)
#pragma unroll
    for (int ks = 0; ks < 8; ++ks)
      afr[jj][ks] = A8[(ks * 8 + jw * 2 + jj) * 64 + l];
  __syncthreads();   // all afr loads done before panel overwrites tile
  issue_chunk(0, 0); // chunk 0 into buf0 (tile region, now dead)
  if (tx < 128) {
    float s = 0.f;
#pragma unroll
    for (int q = 0; q < 8; ++q) s += nfpart[q * 128 + tx];
    nAb[tx] = s;
  }
  __syncthreads();   // chunk-0 loads drained; nAb ready
  float naj[2][4];
#pragma unroll
  for (int jj = 0; jj < 2; ++jj)
#pragma unroll
    for (int rr = 0; rr < 4; ++rr)
      naj[jj][rr] = nAb[jw * 32 + jj * 16 + l4 * 4 + rr];
  // ---- distance loop over 16 i-chunks of 64 (ONE barrier per chunk)
  const float* nBc = nB + (c << 10);
  const size_t obase = (size_t)(c * 8 + jt) * 1024;
  for (int ch = 0; ch < 16; ++ch) {
    if (ch < 15) issue_chunk((ch + 1) & 1, ch + 1);
    const bfv8* B8 = (const bfv8*)(Ab + (ch & 1) * 32768);
    f32x4 a2[2];
    a2[0] = f32x4{0.f, 0.f, 0.f, 0.f};
    a2[1] = f32x4{0.f, 0.f, 0.f, 0.f};
#pragma unroll
    for (int ks = 0; ks < 8; ++ks) {
      bfv8 b = B8[(ks * 4 + iw) * 64 + l];
      a2[0] = __builtin_amdgcn_mfma_f32_16x16x32_bf16(afr[0][ks], b, a2[0], 0, 0, 0);
      a2[1] = __builtin_amdgcn_mfma_f32_16x16x32_bf16(afr[1][ks], b, a2[1], 0, 0, 0);
    }
    const float nb = nBc[ch * 64 + iw * 16 + lm];
    float mm = 3.0e38f;
#pragma unroll
    for (int jj = 0; jj < 2; ++jj)
#pragma unroll
      for (int rr = 0; rr < 4; ++rr) {
        const float dd = nb + naj[jj][rr] - 2.0f * a2[jj][rr];
        mm = fminf(mm, dd);
      }
    mm = fminf(mm, __shfl_xor(mm, 16, 64));
    mm = fminf(mm, __shfl_xor(mm, 32, 64));
    float* mb = minbuf + (ch & 1) * 256;
    if (l4 == 0) mb[jw * 64 + iw * 16 + lm] = mm;
    __syncthreads();   // minbuf bank ready; also bounds panel-dbuf skew
    if (tx < 64) {
      float m = mb[tx];
#pragma unroll
      for (int q = 1; q < 4; ++q) m = fminf(m, mb[q * 64 + tx]);
      pmind[obase + ch * 64 + tx] = m;
    }
    // no second barrier: next chunk writes the OTHER minbuf bank, and any
    // reader here must pass the next barrier before that bank is reused.
  }
}

// K0: blocks 0..255 = convnorm(p2 -> p2b, n2); block 256 = W -> bf16 Wb
__global__ __launch_bounds__(1024, 1) void k0_kernel(
    const float* __restrict__ p2, u16* __restrict__ p2b,
    float* __restrict__ n2, const float* __restrict__ W,
    u16* __restrict__ Wb) {
  if (blockIdx.x < 256) {
    convnorm_role(p2, p2b, n2, blockIdx.x);
  } else {
    const int t = threadIdx.x;
#pragma unroll
    for (int k = 0; k < 64; ++k) Wb[k * 1024 + t] = f2bf(W[k * 1024 + t]);
  }
}

// K1: block 0 = gj; 1..512 = dist dir=1 (F in-block from Wb, panel p2b);
// 513..768 = convnorm p1 -> p1b, n1 (for K3).
__global__ __launch_bounds__(1024, 1) void k1_kernel(
    const float* __restrict__ p1, const float* __restrict__ W,
    const u16* __restrict__ Wb, const float* __restrict__ bv,
    const u16* __restrict__ p2b, const float* __restrict__ n2,
    float* __restrict__ pmin1, float* __restrict__ IWa,
    u16* __restrict__ p1b, float* __restrict__ n1) {
  extern __shared__ char smem[];
  const int b = blockIdx.x;
  if (b == 0) {
    gj_body(W, IWa, smem);
  } else if (b <= 512) {
    distp_body<0>(p1, Wb, bv, p2b, n2, pmin1, b - 1, smem);
  } else {
    convnorm_role(p1, p1b, n1, b - 513);
  }
}

// Fused Newton-Schulz: Y = X(2I - W X) -> bf16. 32 blocks x 8 columns.
__global__ __launch_bounds__(256) void ns_fused(const float* __restrict__ W,
                                                const float* __restrict__ X,
                                                u16* __restrict__ Yb) {
  __shared__ float Xc[256][8];
  __shared__ float Rc[256][8];
  const int jc = blockIdx.x * 8, t = threadIdx.x;
  {
    float4 xa = *(const float4*)&X[(size_t)t * D + jc];
    float4 xb = *(const float4*)&X[(size_t)t * D + jc + 4];
    Xc[t][0] = xa.x; Xc[t][1] = xa.y; Xc[t][2] = xa.z; Xc[t][3] = xa.w;
    Xc[t][4] = xb.x; Xc[t][5] = xb.y; Xc[t][6] = xb.z; Xc[t][7] = xb.w;
  }
  __syncthreads();
  float r[8] = {0.f, 0.f, 0.f, 0.f, 0.f, 0.f, 0.f, 0.f};
#pragma unroll 4
  for (int k = 0; k < D; ++k) {
    const float wv = W[(size_t)t * D + k];
#pragma unroll
    for (int q = 0; q < 8; ++q) r[q] = fmaf(wv, Xc[k][q], r[q]);
  }
#pragma unroll
  for (int q = 0; q < 8; ++q)
    Rc[t][q] = ((t - jc) == q ? 2.0f : 0.0f) - r[q];
  __syncthreads();
  float y[8] = {0.f, 0.f, 0.f, 0.f, 0.f, 0.f, 0.f, 0.f};
#pragma unroll 4
  for (int k = 0; k < D; ++k) {
    const float xv = X[(size_t)t * D + k];
#pragma unroll
    for (int q = 0; q < 8; ++q) y[q] = fmaf(xv, Rc[k][q], y[q]);
  }
#pragma unroll
  for (int q = 0; q < 8; ++q)
    Yb[(size_t)t * D + jc + q] = f2bf(y[q]);
}

// K3: dist dir=0 (Q in-block from IWb; panel p1b + norms n1)
__global__ __launch_bounds__(1024, 1) void k3_kernel(
    const float* __restrict__ p2, const u16* __restrict__ IWb,
    const float* __restrict__ bv, const u16* __restrict__ p1b,
    const float* __restrict__ n1, float* __restrict__ pmin0) {
  extern __shared__ char smem[];
  distp_body<1>(p2, IWb, bv, p1b, n1, pmin0, blockIdx.x, smem);
}

// final: out[dir*64+c] = mean_i min_jt pmin[dir][c][jt][i]
__global__ __launch_bounds__(256) void final_kernel(const float* __restrict__ pmin,
                                                    float* __restrict__ out) {
  __shared__ float ws4[4];
  const int dc = blockIdx.x, tx = threadIdx.x;
  const float* base = pmin + (size_t)dc * 8192;
  float s = 0.f;
#pragma unroll
  for (int t = 0; t < 4; ++t) {
    const int i = t * 256 + tx;
    float m = base[i];
#pragma unroll
    for (int j = 1; j < 8; ++j) m = fminf(m, base[j * 1024 + i]);
    s += m;
  }
#pragma unroll
  for (int off = 32; off; off >>= 1) s += __shfl_xor(s, off, 64);
  if ((tx & 63) == 0) ws4[tx >> 6] = s;
  __syncthreads();
  if (tx == 0)
    out[dc] = (ws4[0] + ws4[1] + ws4[2] + ws4[3]) * (1.0f / 1024.0f);
}

extern "C" void kernel_launch(void* const* d_in, const int* in_sizes, int n_in,
                              void* d_out, int out_size, void* d_ws, size_t ws_size,
                              hipStream_t stream) {
  const float* p1 = (const float*)d_in[0];
  const float* p2 = (const float*)d_in[1];
  const float* W  = (const float*)d_in[2];
  const float* bv = (const float*)d_in[3];
  float* out = (float*)d_out;
  char* ws = (char*)d_ws;
  float* n1  = (float*)(ws);                     // 256KB
  float* n2  = (float*)(ws + (256 << 10));       // 256KB
  u16* Wb    = (u16*)(ws + (512 << 10));         // 128KB
  u16* IWb   = (u16*)(ws + (640 << 10));         // 128KB
  float* IWa = (float*)(ws + (768 << 10));       // 256KB
  float* pmin = (float*)(ws + (1 << 20));        // 4MB: [dir][c][jt][1024]
  u16* p1b   = (u16*)(ws + (6u << 20));          // 32MB class-major bf16
  u16* p2b   = (u16*)(ws + (38u << 20));         // 32MB
  float* pmin0 = pmin;                 // dir 0 (source: p1 vs Q)
  float* pmin1 = pmin + 524288;        // dir 1 (target: p2 vs F)

  hipFuncSetAttribute((const void*)k1_kernel,
                      hipFuncAttributeMaxDynamicSharedMemorySize, K1_LDS);
  hipFuncSetAttribute((const void*)k3_kernel,
                      hipFuncAttributeMaxDynamicSharedMemorySize, DISTP_LDS);

  // K0: p2 convert + norms, W -> bf16
  k0_kernel<<<257, 1024, 0, stream>>>(p2, p2b, n2, W, Wb);
  // K1: gj inverse || dist dir=1 || p1 convert + norms
  k1_kernel<<<769, 1024, K1_LDS, stream>>>(p1, W, Wb, bv, p2b, n2,
                                           pmin1, IWa, p1b, n1);
  // fused Newton-Schulz refinement, bf16 output
  ns_fused<<<32, 256, 0, stream>>>(W, IWa, IWb);
  // K3: dist dir=0 (Q from IWb)
  k3_kernel<<<512, 1024, DISTP_LDS, stream>>>(p2, IWb, bv, p1b, n1, pmin0);
  final_kernel<<<128, 256, 0, stream>>>(pmin, out);
}